// Round 9
// baseline (111.579 us; speedup 1.0000x reference)
//
#include <hip/hip_runtime.h>

#define HH 512
#define WW 512
#define NPIX (HH*WW)
#define KK 16
#define BB 8
#define NB 448   // lovasz error histogram buckets over e in [0,2] (%64==0)
#define CH 32    // pixel chunks per (b, kgroup) in k_histvar
#define KG 4     // instances per k_histvar block
#define NSL (KK*4 + 1)   // 65 partial slots in k_sums

__device__ __forceinline__ float fast_rcp(float x){ return __builtin_amdgcn_rcpf(x); }
__device__ __forceinline__ float fast_tanh(float x){
  x = fminf(fmaxf(x, -15.f), 15.f);
  float t = __expf(2.f*x);
  return (t-1.f)*fast_rcp(t+1.f);
}
__device__ __forceinline__ float fast_sigmoid(float x){
  x = fminf(fmaxf(x, -30.f), 30.f);
  return fast_rcp(1.f+__expf(-x));
}

// ---------------- kernel 1: mask sums -> transposed per-block partials -----
// grid 2048: b = bid&7 (XCD-affine), ch = bid>>3 in [0,256); 1024 px/block.
// unsafeAtomicAdd -> native ds_add_f32 (plain atomicAdd on LDS f32 is a CAS
// retry loop; that CAS traffic was the 44us invariant in R5-R7).
__global__ void __launch_bounds__(256) k_sums(
    const float* __restrict__ pred, const int* __restrict__ inst,
    const int* __restrict__ lab, float* __restrict__ partial_s /*[B][65][256]*/) {
  const int bid = blockIdx.x;
  const int b  = bid & 7;
  const int ch = bid >> 3;
  __shared__ float ls[NSL];
  const int tid = threadIdx.x;
  if (tid < NSL) ls[tid] = 0.f;
  __syncthreads();
  const float inv = 1.f/511.f;
  const float* ps = pred + (size_t)b*4*NPIX + 2*NPIX;  // sigma channel
  const float* pd = ps + NPIX;                          // seed channel
  const int*   ib = inst + (size_t)b*NPIX;
  const int*   lb = lab  + (size_t)b*NPIX;
  const int p = ch*1024 + tid*4;
  int4   iv = *(const int4*)(ib + p);
  int4   lv = *(const int4*)(lb + p);
  float4 sv = *(const float4*)(ps + p);
  float4 dv = *(const float4*)(pd + p);
  const float ym  = (float)(p >> 9) * inv;
  const float xm0 = (float)(p & (WW-1)) * inv;
  int   ida[4] = {iv.x, iv.y, iv.z, iv.w};
  int   laa[4] = {lv.x, lv.y, lv.z, lv.w};
  float sga[4] = {sv.x, sv.y, sv.z, sv.w};
  float sda[4] = {dv.x, dv.y, dv.z, dv.w};
  float sbg = 0.f;
  #pragma unroll
  for (int j = 0; j < 4; ++j) {
    int id = ida[j];
    if (id >= 1) {
      int o = (id-1)*4;
      unsafeAtomicAdd(&ls[o+0], 1.f);
      unsafeAtomicAdd(&ls[o+1], xm0 + (float)j*inv);
      unsafeAtomicAdd(&ls[o+2], ym);
      unsafeAtomicAdd(&ls[o+3], sga[j]);
    }
    if (laa[j] == 0) { float sd = fast_sigmoid(sda[j]); sbg += sd*sd; }
  }
  #pragma unroll
  for (int off = 32; off; off >>= 1) sbg += __shfl_down(sbg, off);
  if ((tid & 63) == 0) unsafeAtomicAdd(&ls[KK*4], sbg);
  __syncthreads();
  if (tid < NSL) partial_s[((size_t)b*NSL + tid)*256 + ch] = ls[tid];
}

// ---------------- kernel 2: reduce partials -> sums, seedbg, der ----------
// grid 8 x 256. Wave w handles slots w, w+4, ...; lane sums 4 chunks coalesced.
__global__ void __launch_bounds__(256) k_reduce(
    const float* __restrict__ partial_s, float* __restrict__ sums,
    float* __restrict__ seedbg, float* __restrict__ der /*[B][K][8]*/) {
  const int b = blockIdx.x;
  const int tid = threadIdx.x;
  const int w = tid >> 6, l = tid & 63;
  __shared__ float lsum[NSL];
  #pragma unroll
  for (int i = 0; i < 17; ++i) {
    int s = w + 4*i;
    if (s < NSL) {
      const float* row = partial_s + ((size_t)b*NSL + s)*256;
      float a = row[l] + row[l+64] + row[l+128] + row[l+192];
      #pragma unroll
      for (int off = 32; off; off >>= 1) a += __shfl_down(a, off);
      if (l == 0) lsum[s] = a;
    }
  }
  __syncthreads();
  if (tid < KK*4) sums[b*KK*4 + tid] = lsum[tid];
  if (tid == KK*4) seedbg[b] = lsum[KK*4];
  if (tid < KK) {
    float cnt  = lsum[tid*4+0];
    float safe = fmaxf(cnt, 1.f);
    float cx = lsum[tid*4+1]/safe;
    float cy = lsum[tid*4+2]/safe;
    float s  = lsum[tid*4+3]/safe;
    float* dd = der + (b*KK + tid)*8;
    dd[0] = cx; dd[1] = cy; dd[2] = s;
    dd[3] = __expf(10.f*s);
    dd[4] = (cnt > 0.f) ? 1.f : 0.f;
    dd[5] = cnt;
  }
}

// ---------------- kernel 3: fused 4-instance histograms + fg var/seed -----
// grid 1024: b = bid&7, kg = (bid>>3)&3, ch = bid>>5 (8192 px per block)
__global__ void __launch_bounds__(256, 4) k_histvar(
    const float* __restrict__ pred, const int* __restrict__ inst,
    const float* __restrict__ der, unsigned int* __restrict__ hist,
    float* __restrict__ partial_v /*[B][K][CH][2]*/) {
  const int bid = blockIdx.x;
  const int b  = bid & 7;
  const int kg = (bid >> 3) & 3;
  const int ch = bid >> 5;
  const int k0 = kg*KG;
  __shared__ unsigned int lh[KG][NB];
  __shared__ float sder[KG][6];   // cx, cy, sexp, act, s
  __shared__ float red[8][4];
  const int tid = threadIdx.x;
  if (tid < KG) {
    const float* dd = der + (b*KK + k0 + tid)*8;
    sder[tid][0] = dd[0]; sder[tid][1] = dd[1];
    sder[tid][2] = dd[3]; sder[tid][3] = dd[4];
    sder[tid][4] = dd[2];
  }
  for (int i = tid; i < KG*NB; i += 256) ((unsigned int*)lh)[i] = 0u;
  __syncthreads();
  const float cx0 = sder[0][0], cy0 = sder[0][1], se0 = sder[0][2], sm0 = sder[0][4];
  const float cx1 = sder[1][0], cy1 = sder[1][1], se1 = sder[1][2], sm1 = sder[1][4];
  const float cx2 = sder[2][0], cy2 = sder[2][1], se2 = sder[2][2], sm2 = sder[2][4];
  const float cx3 = sder[3][0], cy3 = sder[3][1], se3 = sder[3][2], sm3 = sder[3][4];
  const bool a0 = sder[0][3] > 0.f, a1 = sder[1][3] > 0.f;
  const bool a2 = sder[2][3] > 0.f, a3 = sder[3][3] > 0.f;
  const float inv = 1.f/511.f;
  const float* pbx = pred + (size_t)b*4*NPIX;
  const float* pby = pbx + NPIX;
  const float* pbs = pbx + 2*NPIX;
  const float* pbd = pbx + 3*NPIX;
  const int*   ib  = inst + (size_t)b*NPIX;
  const int base = ch * (NPIX/CH);
  float sv0=0.f, sv1=0.f, sv2=0.f, sv3=0.f;   // var partials
  float sq0=0.f, sq1=0.f, sq2=0.f, sq3=0.f;   // seed partials
  #pragma unroll
  for (int it = 0; it < 8; ++it) {            // 8 x 1024 px
    const int p = base + it*1024 + tid*4;
    float4 px = *(const float4*)(pbx + p);
    float4 py = *(const float4*)(pby + p);
    int4   iv = *(const int4*)(ib + p);
    const float ym  = (float)(p >> 9) * inv;
    const float xm0 = (float)(p & (WW-1)) * inv;
    float pxa[4] = {px.x, px.y, px.z, px.w};
    float pya[4] = {py.x, py.y, py.z, py.w};
    int   ida[4] = {iv.x, iv.y, iv.z, iv.w};
    #pragma unroll
    for (int j = 0; j < 4; ++j) {
      float sex = fast_tanh(pxa[j]) + xm0 + (float)j*inv;
      float sey = fast_tanh(pya[j]) + ym;
      int id = ida[j];
      float down = 0.f;                       // d of pixel's own instance
      #define DOK(K, CX, CY, SE, ACT)                                \
        if (ACT) {                                                   \
          float dx = sex - CX, dy = sey - CY;                        \
          float d = __expf(-SE*(dx*dx + dy*dy));                     \
          bool fg = (id == k0 + K + 1);                              \
          float t2 = d + d;                                          \
          float e  = fg ? (2.f - t2) : t2;                           \
          int bkt = (int)(e * (float)(NB/2));                        \
          bkt = bkt < (NB-1) ? bkt : (NB-1);                         \
          bkt = bkt > 0 ? bkt : 0;                                   \
          atomicAdd(&lh[K][bkt], fg ? 0x10001u : 1u);                \
          down = fg ? d : down;                                      \
        }
      DOK(0, cx0, cy0, se0, a0)
      DOK(1, cx1, cy1, se1, a1)
      DOK(2, cx2, cy2, se2, a2)
      DOK(3, cx3, cy3, se3, a3)
      #undef DOK
      int kl = id - 1 - k0;
      if ((unsigned)kl < 4u) {                // own instance handled here
        float sg = pbs[p + j];
        float sd = pbd[p + j];
        float sm = (kl==0) ? sm0 : (kl==1) ? sm1 : (kl==2) ? sm2 : sm3;
        float dsig = sg - sm;
        float dsee = fast_sigmoid(sd) - down;
        float dsq = dsig*dsig, deq = dsee*dsee;
        if (kl == 0) { sv0 += dsq; sq0 += deq; }
        else if (kl == 1) { sv1 += dsq; sq1 += deq; }
        else if (kl == 2) { sv2 += dsq; sq2 += deq; }
        else { sv3 += dsq; sq3 += deq; }
      }
    }
  }
  __syncthreads();
  // flush LDS hist -> private global region (plain coalesced stores)
  #pragma unroll
  for (int k = 0; k < KG; ++k) {
    unsigned int* gh = hist + ((size_t)(b*KK + k0 + k)*CH + ch)*NB;
    for (int i = tid; i < NB; i += 256) gh[i] = lh[k][i];
  }
  // block-reduce the 8 fg accumulators -> plain stores to partial_v
  #pragma unroll
  for (int off = 32; off; off >>= 1) {
    sv0 += __shfl_down(sv0, off); sq0 += __shfl_down(sq0, off);
    sv1 += __shfl_down(sv1, off); sq1 += __shfl_down(sq1, off);
    sv2 += __shfl_down(sv2, off); sq2 += __shfl_down(sq2, off);
    sv3 += __shfl_down(sv3, off); sq3 += __shfl_down(sq3, off);
  }
  const int wid = tid >> 6;
  if ((tid & 63) == 0) {
    red[0][wid] = sv0; red[1][wid] = sq0; red[2][wid] = sv1; red[3][wid] = sq1;
    red[4][wid] = sv2; red[5][wid] = sq2; red[6][wid] = sv3; red[7][wid] = sq3;
  }
  __syncthreads();
  if (tid < 8) {
    int slot = tid >> 1, comp = tid & 1;     // red idx = slot*2+comp
    float v = red[tid][0] + red[tid][1] + red[tid][2] + red[tid][3];
    partial_v[(((size_t)b*KK + k0 + slot)*CH + ch)*2 + comp] = v;
  }
}

// ---------------- kernel 4: lovasz via descending histogram scan ----------
__global__ void __launch_bounds__(64) k_lovasz(
    const unsigned int* __restrict__ hist,
    const float* __restrict__ sums, float* __restrict__ instl) {
  const int seg = blockIdx.x;           // b*K + k
  const float gts = sums[seg*4];
  const int lane = threadIdx.x;         // one wave
  if (gts <= 0.f) { if (lane == 0) instl[seg] = 0.f; return; }
  const unsigned int* h = hist + (size_t)seg*CH*NB;
  float carryN = 0.f, carryF = 0.f, lsum = 0.f;
  for (int it = 0; it < NB/64; ++it) {
    int bkt = NB - 1 - (it*64 + lane);   // descending error order
    unsigned int nlo = 0, nhi = 0;
    #pragma unroll
    for (int q = 0; q < CH; ++q) {
      unsigned int c = h[q*NB + bkt];
      nlo += c & 0xffffu; nhi += c >> 16;
    }
    float nb = (float)nlo, fb = (float)nhi;
    float sn = nb, sf = fb;
    #pragma unroll
    for (int off = 1; off < 64; off <<= 1) {
      float tn = __shfl_up(sn, off);
      float tf = __shfl_up(sf, off);
      if (lane >= off) { sn += tn; sf += tf; }
    }
    float Nb = carryN + sn - nb;        // exclusive prefix
    float Fb = carryF + sf - fb;
    if (nlo) {
      float e  = ((float)bkt + 0.5f) * (2.0f/(float)NB);
      float j0 = 1.f - (gts - Fb) / (gts + Nb - Fb);
      float N1 = Nb + nb, F1 = Fb + fb;
      float j1 = 1.f - (gts - F1) / (gts + N1 - F1);
      lsum += e * (j1 - j0);
    }
    carryN += __shfl(sn, 63);
    carryF += __shfl(sf, 63);
  }
  #pragma unroll
  for (int off = 32; off; off >>= 1) lsum += __shfl_down(lsum, off);
  if (lane == 0) instl[seg] = lsum;
}

// ---------------- kernel 5: vreduce + combine ------------------------------
__global__ void __launch_bounds__(256) k_final(
    const float* __restrict__ partial_v, const float* __restrict__ sums,
    const float* __restrict__ instl, const float* __restrict__ seedbg,
    float* __restrict__ out) {
  __shared__ float vsum[256];           // [b][k][comp] reduced over ch
  const int tid = threadIdx.x;
  {
    const int b = tid >> 5, k = (tid & 31) >> 1, comp = tid & 1;
    const float* pv = partial_v + (((size_t)b*KK + k)*CH)*2 + comp;
    float a = 0.f;
    #pragma unroll
    for (int ch = 0; ch < CH; ++ch) a += pv[ch*2];
    vsum[tid] = a;
  }
  __syncthreads();
  float myv = 0.f;
  if (tid < BB) {
    int b = tid;
    float obj = 0.f, il = 0.f, vr = 0.f, sl = 0.f;
    for (int k = 0; k < KK; ++k) {
      float cnt = sums[(b*KK + k)*4];
      if (cnt > 0.f) {
        obj += 1.f;
        il  += instl[b*KK + k];
        vr  += vsum[b*32 + k*2 + 0] / cnt;   // var/(N_SIGMA*safe), safe==cnt
        sl  += vsum[b*32 + k*2 + 1];         // FG_W == 1
      }
    }
    float so = fmaxf(obj, 1.f);
    myv = il/so + 10.f*vr/so + (seedbg[b] + sl)/(float)NPIX;
  }
  #pragma unroll
  for (int off = 4; off; off >>= 1) myv += __shfl_down(myv, off);
  if (tid == 0) out[0] = myv * (1.f/(float)BB);
}

extern "C" void kernel_launch(void* const* d_in, const int* in_sizes, int n_in,
                              void* d_out, int out_size, void* d_ws, size_t ws_size,
                              hipStream_t stream) {
  const float* pred = (const float*)d_in[0];
  const int*   inst = (const int*)d_in[1];
  const int*   lab  = (const int*)d_in[2];
  float* out = (float*)d_out;

  // scalar region [0, 8192): all fully overwritten every call (no memset).
  float* sums   = (float*)d_ws;                          // 512 f32 @ 0
  float* seedbg = (float*)((char*)d_ws + 2048);          // 8 f32
  float* der    = (float*)((char*)d_ws + 2112);          // 128*8 f32
  float* instl  = (float*)((char*)d_ws + 6208);          // 128 f32
  // [8192, +7,340,032): hist (128 segs * 32 ch * 448 * 4B)
  unsigned int* hist = (unsigned int*)((char*)d_ws + 8192);
  // disjoint tails (all within proven 8,396,800 B budget):
  float* partial_v = (float*)((char*)d_ws + 7348224);    // 8*16*32*2 f32 (32KB)
  float* partial_s = (float*)((char*)d_ws + 7380992);    // 8*65*256 f32 (520KB)

  k_sums   <<<BB*256, 256, 0, stream>>>(pred, inst, lab, partial_s);
  k_reduce <<<BB, 256, 0, stream>>>(partial_s, sums, seedbg, der);
  k_histvar<<<BB*KG*CH, 256, 0, stream>>>(pred, inst, der, hist, partial_v);
  k_lovasz <<<BB*KK, 64, 0, stream>>>(hist, sums, instl);
  k_final  <<<1, 256, 0, stream>>>(partial_v, sums, instl, seedbg, out);
}

// Round 11
// 110.634 us; speedup vs baseline: 1.0085x; 1.0085x over previous
//
#include <hip/hip_runtime.h>

#define HH 512
#define WW 512
#define NPIX (HH*WW)
#define KK 16
#define BB 8
#define NB 192   // lovasz error histogram buckets over e in [0,2] (%64==0)
#define CH 64    // pixel chunks per (b, kgroup) in k_histvar
#define KG 4     // instances per k_histvar block

__device__ __forceinline__ float fast_rcp(float x){ return __builtin_amdgcn_rcpf(x); }
__device__ __forceinline__ float fast_tanh(float x){
  x = fminf(fmaxf(x, -15.f), 15.f);
  float t = __expf(2.f*x);
  return (t-1.f)*fast_rcp(t+1.f);
}
__device__ __forceinline__ float fast_sigmoid(float x){
  x = fminf(fmaxf(x, -30.f), 30.f);
  return fast_rcp(1.f+__expf(-x));
}

// ---------------- kernel 1a: instance mask sums (inst + sigma only) --------
// grid 2048: b = bid&7 (XCD-affine), ch = bid>>3 in [0,256); 1024 px/block.
// 2-stream version: discriminates stream-mix vs LDS-atomic theories.
__global__ void __launch_bounds__(256) k_sums_a(
    const float* __restrict__ pred, const int* __restrict__ inst,
    float* __restrict__ partial_s /*[B][64][256]*/) {
  const int bid = blockIdx.x;
  const int b  = bid & 7;
  const int ch = bid >> 3;
  __shared__ float ls[KK*4];
  const int tid = threadIdx.x;
  if (tid < KK*4) ls[tid] = 0.f;
  __syncthreads();
  const float inv = 1.f/511.f;
  const float* ps = pred + (size_t)b*4*NPIX + 2*NPIX;  // sigma channel
  const int*   ib = inst + (size_t)b*NPIX;
  const int p = ch*1024 + tid*4;
  int4   iv = *(const int4*)(ib + p);
  float4 sv = *(const float4*)(ps + p);
  const float ym  = (float)(p >> 9) * inv;
  const float xm0 = (float)(p & (WW-1)) * inv;
  int   ida[4] = {iv.x, iv.y, iv.z, iv.w};
  float sga[4] = {sv.x, sv.y, sv.z, sv.w};
  #pragma unroll
  for (int j = 0; j < 4; ++j) {
    int id = ida[j];
    if (id >= 1) {
      int o = (id-1)*4;
      atomicAdd(&ls[o+0], 1.f);
      atomicAdd(&ls[o+1], xm0 + (float)j*inv);
      atomicAdd(&ls[o+2], ym);
      atomicAdd(&ls[o+3], sga[j]);
    }
  }
  __syncthreads();
  if (tid < KK*4) partial_s[((size_t)b*64 + tid)*256 + ch] = ls[tid];
}

// ---------------- kernel 1b: bg seed sum (lab + seed only, NO atomics) -----
// grid 2048: same mapping; per-wave shfl reduce -> 4 plain stores per block.
__global__ void __launch_bounds__(256) k_sums_b(
    const float* __restrict__ pred, const int* __restrict__ lab,
    float* __restrict__ partial_b /*[2048][4]*/) {
  const int bid = blockIdx.x;
  const int b  = bid & 7;
  const int ch = bid >> 3;
  const int tid = threadIdx.x;
  const float* pd = pred + (size_t)b*4*NPIX + 3*NPIX;  // seed channel
  const int*   lb = lab  + (size_t)b*NPIX;
  const int p = ch*1024 + tid*4;
  int4   lv = *(const int4*)(lb + p);
  float4 dv = *(const float4*)(pd + p);
  int   laa[4] = {lv.x, lv.y, lv.z, lv.w};
  float sda[4] = {dv.x, dv.y, dv.z, dv.w};
  float sbg = 0.f;
  #pragma unroll
  for (int j = 0; j < 4; ++j) {
    if (laa[j] == 0) { float sd = fast_sigmoid(sda[j]); sbg += sd*sd; }
  }
  #pragma unroll
  for (int off = 32; off; off >>= 1) sbg += __shfl_down(sbg, off);
  if ((tid & 63) == 0) partial_b[bid*4 + (tid >> 6)] = sbg;
}

// ---------------- kernel 2: reduce partials -> sums, seedbg, der ----------
// grid 8 x 256. Wave w handles slots w, w+4, ...; lane sums 4 chunks coalesced.
__global__ void __launch_bounds__(256) k_reduce(
    const float* __restrict__ partial_s, const float* __restrict__ partial_b,
    float* __restrict__ sums, float* __restrict__ seedbg,
    float* __restrict__ der /*[B][K][8]*/) {
  const int b = blockIdx.x;
  const int tid = threadIdx.x;
  const int w = tid >> 6, l = tid & 63;
  __shared__ float lsum[KK*4];
  __shared__ float lsb[4];
  #pragma unroll
  for (int i = 0; i < 16; ++i) {
    int s = w + 4*i;
    const float* row = partial_s + ((size_t)b*64 + s)*256;
    float a = row[l] + row[l+64] + row[l+128] + row[l+192];
    #pragma unroll
    for (int off = 32; off; off >>= 1) a += __shfl_down(a, off);
    if (l == 0) lsum[s] = a;
  }
  // reduce partial_b: entry (ch*8+b)*4+w2 for ch in [0,256), w2 in [0,4)
  {
    const float* pb4 = partial_b + ((size_t)tid*8 + b)*4;
    float a = pb4[0] + pb4[1] + pb4[2] + pb4[3];
    #pragma unroll
    for (int off = 32; off; off >>= 1) a += __shfl_down(a, off);
    if (l == 0) lsb[w] = a;
  }
  __syncthreads();
  if (tid < KK*4) sums[b*KK*4 + tid] = lsum[tid];
  if (tid == 64) seedbg[b] = lsb[0] + lsb[1] + lsb[2] + lsb[3];
  if (tid < KK) {
    float cnt  = lsum[tid*4+0];
    float safe = fmaxf(cnt, 1.f);
    float cx = lsum[tid*4+1]/safe;
    float cy = lsum[tid*4+2]/safe;
    float s  = lsum[tid*4+3]/safe;
    float* dd = der + (b*KK + tid)*8;
    dd[0] = cx; dd[1] = cy; dd[2] = s;
    dd[3] = __expf(10.f*s);
    dd[4] = (cnt > 0.f) ? 1.f : 0.f;
    dd[5] = cnt;
  }
}

// ---------------- kernel 3: fused 4-instance histograms + fg var/seed -----
// grid 2048: b = bid&7, kg = (bid>>3)&3, ch = bid>>5 in [0,64); 4096 px/block
__global__ void __launch_bounds__(256, 8) k_histvar(
    const float* __restrict__ pred, const int* __restrict__ inst,
    const float* __restrict__ der, unsigned int* __restrict__ hist,
    float* __restrict__ partial_v /*[B][K][CH][2]*/) {
  const int bid = blockIdx.x;
  const int b  = bid & 7;
  const int kg = (bid >> 3) & 3;
  const int ch = bid >> 5;
  const int k0 = kg*KG;
  __shared__ unsigned int lh[KG][NB];
  __shared__ float sder[KG][6];   // cx, cy, sexp, act, s
  __shared__ float red[8][4];
  const int tid = threadIdx.x;
  if (tid < KG) {
    const float* dd = der + (b*KK + k0 + tid)*8;
    sder[tid][0] = dd[0]; sder[tid][1] = dd[1];
    sder[tid][2] = dd[3]; sder[tid][3] = dd[4];
    sder[tid][4] = dd[2];
  }
  for (int i = tid; i < KG*NB; i += 256) ((unsigned int*)lh)[i] = 0u;
  __syncthreads();
  const float cx0 = sder[0][0], cy0 = sder[0][1], se0 = sder[0][2], sm0 = sder[0][4];
  const float cx1 = sder[1][0], cy1 = sder[1][1], se1 = sder[1][2], sm1 = sder[1][4];
  const float cx2 = sder[2][0], cy2 = sder[2][1], se2 = sder[2][2], sm2 = sder[2][4];
  const float cx3 = sder[3][0], cy3 = sder[3][1], se3 = sder[3][2], sm3 = sder[3][4];
  const bool a0 = sder[0][3] > 0.f, a1 = sder[1][3] > 0.f;
  const bool a2 = sder[2][3] > 0.f, a3 = sder[3][3] > 0.f;
  const float inv = 1.f/511.f;
  const float* pbx = pred + (size_t)b*4*NPIX;
  const float* pby = pbx + NPIX;
  const float* pbs = pbx + 2*NPIX;
  const float* pbd = pbx + 3*NPIX;
  const int*   ib  = inst + (size_t)b*NPIX;
  const int base = ch * (NPIX/CH);
  float sv0=0.f, sv1=0.f, sv2=0.f, sv3=0.f;   // var partials
  float sq0=0.f, sq1=0.f, sq2=0.f, sq3=0.f;   // seed partials
  #pragma unroll
  for (int it = 0; it < 4; ++it) {            // 4 x 1024 px
    const int p = base + it*1024 + tid*4;
    float4 px = *(const float4*)(pbx + p);
    float4 py = *(const float4*)(pby + p);
    int4   iv = *(const int4*)(ib + p);
    const float ym  = (float)(p >> 9) * inv;
    const float xm0 = (float)(p & (WW-1)) * inv;
    float pxa[4] = {px.x, px.y, px.z, px.w};
    float pya[4] = {py.x, py.y, py.z, py.w};
    int   ida[4] = {iv.x, iv.y, iv.z, iv.w};
    #pragma unroll
    for (int j = 0; j < 4; ++j) {
      float sex = fast_tanh(pxa[j]) + xm0 + (float)j*inv;
      float sey = fast_tanh(pya[j]) + ym;
      int id = ida[j];
      float down = 0.f;                       // d of pixel's own instance
      // u = fg ? 1-d : d in [0,1]; bkt = min(int(u*NB), NB-1)
      #define DOK(K, CX, CY, SE, ACT)                                \
        if (ACT) {                                                   \
          float dx = sex - CX, dy = sey - CY;                        \
          float d = __expf(-SE*(dx*dx + dy*dy));                     \
          bool fg = (id == k0 + K + 1);                              \
          float u  = fg ? (1.f - d) : d;                             \
          int bkt = (int)(u * (float)NB);                            \
          bkt = bkt < (NB-1) ? bkt : (NB-1);                         \
          atomicAdd(&lh[K][bkt], fg ? 0x10001u : 1u);                \
          down = fg ? d : down;                                      \
        }
      DOK(0, cx0, cy0, se0, a0)
      DOK(1, cx1, cy1, se1, a1)
      DOK(2, cx2, cy2, se2, a2)
      DOK(3, cx3, cy3, se3, a3)
      #undef DOK
      int kl = id - 1 - k0;
      if ((unsigned)kl < 4u) {                // own instance handled here
        float sg = pbs[p + j];
        float sd = pbd[p + j];
        float sm = (kl==0) ? sm0 : (kl==1) ? sm1 : (kl==2) ? sm2 : sm3;
        float dsig = sg - sm;
        float dsee = fast_sigmoid(sd) - down;
        float dsq = dsig*dsig, deq = dsee*dsee;
        if (kl == 0) { sv0 += dsq; sq0 += deq; }
        else if (kl == 1) { sv1 += dsq; sq1 += deq; }
        else if (kl == 2) { sv2 += dsq; sq2 += deq; }
        else { sv3 += dsq; sq3 += deq; }
      }
    }
  }
  __syncthreads();
  // flush LDS hist -> private global region (plain coalesced stores)
  #pragma unroll
  for (int k = 0; k < KG; ++k) {
    unsigned int* gh = hist + ((size_t)(b*KK + k0 + k)*CH + ch)*NB;
    for (int i = tid; i < NB; i += 256) if (i < NB) gh[i] = lh[k][i];
  }
  // block-reduce the 8 fg accumulators -> plain stores to partial_v
  #pragma unroll
  for (int off = 32; off; off >>= 1) {
    sv0 += __shfl_down(sv0, off); sq0 += __shfl_down(sq0, off);
    sv1 += __shfl_down(sv1, off); sq1 += __shfl_down(sq1, off);
    sv2 += __shfl_down(sv2, off); sq2 += __shfl_down(sq2, off);
    sv3 += __shfl_down(sv3, off); sq3 += __shfl_down(sq3, off);
  }
  const int wid = tid >> 6;
  if ((tid & 63) == 0) {
    red[0][wid] = sv0; red[1][wid] = sq0; red[2][wid] = sv1; red[3][wid] = sq1;
    red[4][wid] = sv2; red[5][wid] = sq2; red[6][wid] = sv3; red[7][wid] = sq3;
  }
  __syncthreads();
  if (tid < 8) {
    int slot = tid >> 1, comp = tid & 1;     // red idx = slot*2+comp
    float v = red[tid][0] + red[tid][1] + red[tid][2] + red[tid][3];
    partial_v[(((size_t)b*KK + k0 + slot)*CH + ch)*2 + comp] = v;
  }
}

// ---------------- kernel 4: lovasz via descending histogram scan ----------
__global__ void __launch_bounds__(64) k_lovasz(
    const unsigned int* __restrict__ hist,
    const float* __restrict__ sums, float* __restrict__ instl) {
  const int seg = blockIdx.x;           // b*K + k
  const float gts = sums[seg*4];
  const int lane = threadIdx.x;         // one wave
  if (gts <= 0.f) { if (lane == 0) instl[seg] = 0.f; return; }
  const unsigned int* h = hist + (size_t)seg*CH*NB;
  float carryN = 0.f, carryF = 0.f, lsum = 0.f;
  for (int it = 0; it < NB/64; ++it) {
    int bkt = NB - 1 - (it*64 + lane);   // descending error order
    unsigned int nlo = 0, nhi = 0;
    #pragma unroll
    for (int q = 0; q < CH; ++q) {
      unsigned int c = h[q*NB + bkt];
      nlo += c & 0xffffu; nhi += c >> 16;
    }
    float nb = (float)nlo, fb = (float)nhi;
    float sn = nb, sf = fb;
    #pragma unroll
    for (int off = 1; off < 64; off <<= 1) {
      float tn = __shfl_up(sn, off);
      float tf = __shfl_up(sf, off);
      if (lane >= off) { sn += tn; sf += tf; }
    }
    float Nb = carryN + sn - nb;        // exclusive prefix
    float Fb = carryF + sf - fb;
    if (nlo) {
      float e  = ((float)bkt + 0.5f) * (2.0f/(float)NB);
      float j0 = 1.f - (gts - Fb) / (gts + Nb - Fb);
      float N1 = Nb + nb, F1 = Fb + fb;
      float j1 = 1.f - (gts - F1) / (gts + N1 - F1);
      lsum += e * (j1 - j0);
    }
    carryN += __shfl(sn, 63);
    carryF += __shfl(sf, 63);
  }
  #pragma unroll
  for (int off = 32; off; off >>= 1) lsum += __shfl_down(lsum, off);
  if (lane == 0) instl[seg] = lsum;
}

// ---------------- kernel 5: vreduce + combine ------------------------------
__global__ void __launch_bounds__(256) k_final(
    const float* __restrict__ partial_v, const float* __restrict__ sums,
    const float* __restrict__ instl, const float* __restrict__ seedbg,
    float* __restrict__ out) {
  __shared__ float vsum[256];           // [b][k][comp] reduced over ch
  const int tid = threadIdx.x;
  {
    const int b = tid >> 5, k = (tid & 31) >> 1, comp = tid & 1;
    const float* pv = partial_v + (((size_t)b*KK + k)*CH)*2 + comp;
    float a = 0.f;
    #pragma unroll
    for (int ch = 0; ch < CH; ++ch) a += pv[ch*2];
    vsum[tid] = a;
  }
  __syncthreads();
  float myv = 0.f;
  if (tid < BB) {
    int b = tid;
    float obj = 0.f, il = 0.f, vr = 0.f, sl = 0.f;
    for (int k = 0; k < KK; ++k) {
      float cnt = sums[(b*KK + k)*4];
      if (cnt > 0.f) {
        obj += 1.f;
        il  += instl[b*KK + k];
        vr  += vsum[b*32 + k*2 + 0] / cnt;   // var/(N_SIGMA*safe), safe==cnt
        sl  += vsum[b*32 + k*2 + 1];         // FG_W == 1
      }
    }
    float so = fmaxf(obj, 1.f);
    myv = il/so + 10.f*vr/so + (seedbg[b] + sl)/(float)NPIX;
  }
  #pragma unroll
  for (int off = 4; off; off >>= 1) myv += __shfl_down(myv, off);
  if (tid == 0) out[0] = myv * (1.f/(float)BB);
}

extern "C" void kernel_launch(void* const* d_in, const int* in_sizes, int n_in,
                              void* d_out, int out_size, void* d_ws, size_t ws_size,
                              hipStream_t stream) {
  const float* pred = (const float*)d_in[0];
  const int*   inst = (const int*)d_in[1];
  const int*   lab  = (const int*)d_in[2];
  float* out = (float*)d_out;

  // scalar region [0, 8192): all fully overwritten every call (no memset).
  float* sums   = (float*)d_ws;                          // 512 f32 @ 0
  float* seedbg = (float*)((char*)d_ws + 2048);          // 8 f32
  float* der    = (float*)((char*)d_ws + 2112);          // 128*8 f32
  float* instl  = (float*)((char*)d_ws + 6208);          // 128 f32
  // hist: 128 segs * 64 ch * 192 * 4B = 6,291,456 B @ [8192, 6299648)
  unsigned int* hist = (unsigned int*)((char*)d_ws + 8192);
  float* partial_v = (float*)((char*)d_ws + 6299648);    // 128*64*2 f32 (64KB)
  float* partial_s = (float*)((char*)d_ws + 6365184);    // 8*64*256 f32 (512KB)
  float* partial_b = (float*)((char*)d_ws + 6889472);    // 2048*4 f32 (32KB)
  // total 6,922,240 B — within proven 8,396,800 budget

  k_sums_a <<<BB*256, 256, 0, stream>>>(pred, inst, partial_s);
  k_sums_b <<<BB*256, 256, 0, stream>>>(pred, lab, partial_b);
  k_reduce <<<BB, 256, 0, stream>>>(partial_s, partial_b, sums, seedbg, der);
  k_histvar<<<BB*KG*CH, 256, 0, stream>>>(pred, inst, der, hist, partial_v);
  k_lovasz <<<BB*KK, 64, 0, stream>>>(hist, sums, instl);
  k_final  <<<1, 256, 0, stream>>>(partial_v, sums, instl, seedbg, out);
}

// Round 14
// 93.817 us; speedup vs baseline: 1.1893x; 1.1793x over previous
//
#include <hip/hip_runtime.h>

#define HH 512
#define WW 512
#define NPIX (HH*WW)
#define KK 16
#define BB 8
#define NB 192   // lovasz error histogram buckets (%64==0)
#define CH 64    // pixel chunks per (b, kgroup) in k_histvar
#define KG 4     // instances per k_histvar block

__device__ __forceinline__ float fast_rcp(float x){ return __builtin_amdgcn_rcpf(x); }
__device__ __forceinline__ float fast_tanh(float x){
  x = fminf(fmaxf(x, -15.f), 15.f);
  float t = __expf(2.f*x);
  return (t-1.f)*fast_rcp(t+1.f);
}
__device__ __forceinline__ float fast_sigmoid(float x){
  x = fminf(fmaxf(x, -30.f), 30.f);
  return fast_rcp(1.f+__expf(-x));
}

// ---------------- kernel 1: mask sums + bg seed, ZERO atomics --------------
// grid 2048: b = bid&7 (XCD-affine), ch = bid>>3; 1024 px/block, 4 px/lane.
// Per-k predicated lane-condense + 4-level shfl butterfly (16-lane groups);
// group leaders write disjoint LDS slots. R11 discriminator showed the LDS
// atomicAdd scatter (same-address RMW serialization) was the whole 44us.
__global__ void __launch_bounds__(256) k_sums(
    const float* __restrict__ pred, const int* __restrict__ inst,
    const int* __restrict__ lab, float* __restrict__ partial_s /*[B][64][256]*/,
    float* __restrict__ partial_b /*[2048]*/) {
  const int bid = blockIdx.x;
  const int b  = bid & 7;
  const int ch = bid >> 3;
  const int tid = threadIdx.x;
  const int wave = tid >> 6, lane = tid & 63;
  __shared__ float lred[KK][16][4];   // [k][wave*4+group][comp], 4KB
  __shared__ float lbg[4];
  const float inv = 1.f/511.f;
  const float* ps = pred + (size_t)b*4*NPIX + 2*NPIX;  // sigma channel
  const float* pd = ps + NPIX;                          // seed channel
  const int*   ib = inst + (size_t)b*NPIX;
  const int*   lb = lab  + (size_t)b*NPIX;
  const int p = ch*1024 + tid*4;
  int4   iv = *(const int4*)(ib + p);
  int4   lv = *(const int4*)(lb + p);
  float4 sv = *(const float4*)(ps + p);
  float4 dv = *(const float4*)(pd + p);
  const float ym  = (float)(p >> 9) * inv;    // 4 px of a lane share a row
  const float xm0 = (float)(p & (WW-1)) * inv;
  int   ida[4] = {iv.x, iv.y, iv.z, iv.w};
  int   laa[4] = {lv.x, lv.y, lv.z, lv.w};
  float sga[4] = {sv.x, sv.y, sv.z, sv.w};
  float sda[4] = {dv.x, dv.y, dv.z, dv.w};
  float xja[4] = {xm0, xm0+inv, xm0+2.f*inv, xm0+3.f*inv};

  // bg seed: pure register + shfl reduce (proven fast in R11 k_sums_b)
  float sbg = 0.f;
  #pragma unroll
  for (int j = 0; j < 4; ++j)
    if (laa[j] == 0) { float sd = fast_sigmoid(sda[j]); sbg += sd*sd; }
  #pragma unroll
  for (int off = 32; off; off >>= 1) sbg += __shfl_down(sbg, off);
  if (lane == 0) lbg[wave] = sbg;

  // per-instance sums: lane condense -> 16-lane-group butterfly -> LDS slot
  #pragma unroll
  for (int k = 0; k < KK; ++k) {
    float c = 0.f, sx = 0.f, ss = 0.f;
    #pragma unroll
    for (int j = 0; j < 4; ++j) {
      float m = (ida[j] == k+1) ? 1.f : 0.f;
      c  += m;
      sx = fmaf(m, xja[j], sx);
      ss = fmaf(m, sga[j], ss);
    }
    float sy = c * ym;
    #pragma unroll
    for (int off = 1; off < 16; off <<= 1) {
      c  += __shfl_xor(c,  off);
      sx += __shfl_xor(sx, off);
      sy += __shfl_xor(sy, off);
      ss += __shfl_xor(ss, off);
    }
    if ((lane & 15) == 0) {
      int g = wave*4 + (lane >> 4);
      lred[k][g][0] = c;  lred[k][g][1] = sx;
      lred[k][g][2] = sy; lred[k][g][3] = ss;
    }
  }
  __syncthreads();
  if (tid < 64) {          // slot = k*4+comp; sum 16 group partials
    const int k = tid >> 2, comp = tid & 3;
    float a = 0.f;
    #pragma unroll
    for (int g = 0; g < 16; ++g) a += lred[k][g][comp];
    partial_s[((size_t)b*64 + tid)*256 + ch] = a;
  }
  if (tid == 64) partial_b[bid] = lbg[0] + lbg[1] + lbg[2] + lbg[3];
}

// ---------------- kernel 2: reduce partials -> sums, seedbg, der ----------
// grid 8 x 256. Wave w handles slots w, w+4, ...; lane sums 4 chunks coalesced.
__global__ void __launch_bounds__(256) k_reduce(
    const float* __restrict__ partial_s, const float* __restrict__ partial_b,
    float* __restrict__ sums, float* __restrict__ seedbg,
    float* __restrict__ der /*[B][K][8]*/) {
  const int b = blockIdx.x;
  const int tid = threadIdx.x;
  const int w = tid >> 6, l = tid & 63;
  __shared__ float lsum[KK*4];
  __shared__ float lsb[4];
  #pragma unroll
  for (int i = 0; i < 16; ++i) {
    int s = w + 4*i;
    const float* row = partial_s + ((size_t)b*64 + s)*256;
    float a = row[l] + row[l+64] + row[l+128] + row[l+192];
    #pragma unroll
    for (int off = 32; off; off >>= 1) a += __shfl_down(a, off);
    if (l == 0) lsum[s] = a;
  }
  // reduce partial_b: block bid = ch*8+b wrote partial_b[bid]; ch = tid
  {
    float a = partial_b[(size_t)tid*8 + b];
    #pragma unroll
    for (int off = 32; off; off >>= 1) a += __shfl_down(a, off);
    if (l == 0) lsb[w] = a;
  }
  __syncthreads();
  if (tid < KK*4) sums[b*KK*4 + tid] = lsum[tid];
  if (tid == 64) seedbg[b] = lsb[0] + lsb[1] + lsb[2] + lsb[3];
  if (tid < KK) {
    float cnt  = lsum[tid*4+0];
    float safe = fmaxf(cnt, 1.f);
    float cx = lsum[tid*4+1]/safe;
    float cy = lsum[tid*4+2]/safe;
    float s  = lsum[tid*4+3]/safe;
    float* dd = der + (b*KK + tid)*8;
    dd[0] = cx; dd[1] = cy; dd[2] = s;
    dd[3] = __expf(10.f*s);
    dd[4] = (cnt > 0.f) ? 1.f : 0.f;
    dd[5] = cnt;
  }
}

// ---------------- kernel 3: fused 4-instance histograms + fg var/seed -----
// grid 2048: b = bid&7, kg = (bid>>3)&3, ch = bid>>5 in [0,64); 4096 px/block
__global__ void __launch_bounds__(256, 8) k_histvar(
    const float* __restrict__ pred, const int* __restrict__ inst,
    const float* __restrict__ der, unsigned int* __restrict__ hist,
    float* __restrict__ partial_v /*[B][K][CH][2]*/) {
  const int bid = blockIdx.x;
  const int b  = bid & 7;
  const int kg = (bid >> 3) & 3;
  const int ch = bid >> 5;
  const int k0 = kg*KG;
  __shared__ unsigned int lh[KG][NB];
  __shared__ float sder[KG][6];   // cx, cy, sexp, act, s
  __shared__ float red[8][4];
  const int tid = threadIdx.x;
  if (tid < KG) {
    const float* dd = der + (b*KK + k0 + tid)*8;
    sder[tid][0] = dd[0]; sder[tid][1] = dd[1];
    sder[tid][2] = dd[3]; sder[tid][3] = dd[4];
    sder[tid][4] = dd[2];
  }
  for (int i = tid; i < KG*NB; i += 256) ((unsigned int*)lh)[i] = 0u;
  __syncthreads();
  const float cx0 = sder[0][0], cy0 = sder[0][1], se0 = sder[0][2], sm0 = sder[0][4];
  const float cx1 = sder[1][0], cy1 = sder[1][1], se1 = sder[1][2], sm1 = sder[1][4];
  const float cx2 = sder[2][0], cy2 = sder[2][1], se2 = sder[2][2], sm2 = sder[2][4];
  const float cx3 = sder[3][0], cy3 = sder[3][1], se3 = sder[3][2], sm3 = sder[3][4];
  const bool a0 = sder[0][3] > 0.f, a1 = sder[1][3] > 0.f;
  const bool a2 = sder[2][3] > 0.f, a3 = sder[3][3] > 0.f;
  const float inv = 1.f/511.f;
  const float* pbx = pred + (size_t)b*4*NPIX;
  const float* pby = pbx + NPIX;
  const float* pbs = pbx + 2*NPIX;
  const float* pbd = pbx + 3*NPIX;
  const int*   ib  = inst + (size_t)b*NPIX;
  const int base = ch * (NPIX/CH);
  float sv0=0.f, sv1=0.f, sv2=0.f, sv3=0.f;   // var partials
  float sq0=0.f, sq1=0.f, sq2=0.f, sq3=0.f;   // seed partials
  #pragma unroll
  for (int it = 0; it < 4; ++it) {            // 4 x 1024 px
    const int p = base + it*1024 + tid*4;
    float4 px = *(const float4*)(pbx + p);
    float4 py = *(const float4*)(pby + p);
    int4   iv = *(const int4*)(ib + p);
    const float ym  = (float)(p >> 9) * inv;
    const float xm0 = (float)(p & (WW-1)) * inv;
    float pxa[4] = {px.x, px.y, px.z, px.w};
    float pya[4] = {py.x, py.y, py.z, py.w};
    int   ida[4] = {iv.x, iv.y, iv.z, iv.w};
    #pragma unroll
    for (int j = 0; j < 4; ++j) {
      float sex = fast_tanh(pxa[j]) + xm0 + (float)j*inv;
      float sey = fast_tanh(pya[j]) + ym;
      int id = ida[j];
      float down = 0.f;                       // d of pixel's own instance
      #define DOK(K, CX, CY, SE, ACT)                                \
        if (ACT) {                                                   \
          float dx = sex - CX, dy = sey - CY;                        \
          float d = __expf(-SE*(dx*dx + dy*dy));                     \
          bool fg = (id == k0 + K + 1);                              \
          float u  = fg ? (1.f - d) : d;                             \
          int bkt = (int)(u * (float)NB);                            \
          bkt = bkt < (NB-1) ? bkt : (NB-1);                         \
          atomicAdd(&lh[K][bkt], fg ? 0x10001u : 1u);                \
          down = fg ? d : down;                                      \
        }
      DOK(0, cx0, cy0, se0, a0)
      DOK(1, cx1, cy1, se1, a1)
      DOK(2, cx2, cy2, se2, a2)
      DOK(3, cx3, cy3, se3, a3)
      #undef DOK
      int kl = id - 1 - k0;
      if ((unsigned)kl < 4u) {                // own instance handled here
        float sg = pbs[p + j];
        float sd = pbd[p + j];
        float sm = (kl==0) ? sm0 : (kl==1) ? sm1 : (kl==2) ? sm2 : sm3;
        float dsig = sg - sm;
        float dsee = fast_sigmoid(sd) - down;
        float dsq = dsig*dsig, deq = dsee*dsee;
        if (kl == 0) { sv0 += dsq; sq0 += deq; }
        else if (kl == 1) { sv1 += dsq; sq1 += deq; }
        else if (kl == 2) { sv2 += dsq; sq2 += deq; }
        else { sv3 += dsq; sq3 += deq; }
      }
    }
  }
  __syncthreads();
  // flush LDS hist -> private global region (plain coalesced stores)
  #pragma unroll
  for (int k = 0; k < KG; ++k) {
    unsigned int* gh = hist + ((size_t)(b*KK + k0 + k)*CH + ch)*NB;
    for (int i = tid; i < NB; i += 256) if (i < NB) gh[i] = lh[k][i];
  }
  // block-reduce the 8 fg accumulators -> plain stores to partial_v
  #pragma unroll
  for (int off = 32; off; off >>= 1) {
    sv0 += __shfl_down(sv0, off); sq0 += __shfl_down(sq0, off);
    sv1 += __shfl_down(sv1, off); sq1 += __shfl_down(sq1, off);
    sv2 += __shfl_down(sv2, off); sq2 += __shfl_down(sq2, off);
    sv3 += __shfl_down(sv3, off); sq3 += __shfl_down(sq3, off);
  }
  const int wid = tid >> 6;
  if ((tid & 63) == 0) {
    red[0][wid] = sv0; red[1][wid] = sq0; red[2][wid] = sv1; red[3][wid] = sq1;
    red[4][wid] = sv2; red[5][wid] = sq2; red[6][wid] = sv3; red[7][wid] = sq3;
  }
  __syncthreads();
  if (tid < 8) {
    int slot = tid >> 1, comp = tid & 1;     // red idx = slot*2+comp
    float v = red[tid][0] + red[tid][1] + red[tid][2] + red[tid][3];
    partial_v[(((size_t)b*KK + k0 + slot)*CH + ch)*2 + comp] = v;
  }
}

// ---------------- kernel 4: lovasz via descending histogram scan ----------
__global__ void __launch_bounds__(64) k_lovasz(
    const unsigned int* __restrict__ hist,
    const float* __restrict__ sums, float* __restrict__ instl) {
  const int seg = blockIdx.x;           // b*K + k
  const float gts = sums[seg*4];
  const int lane = threadIdx.x;         // one wave
  if (gts <= 0.f) { if (lane == 0) instl[seg] = 0.f; return; }
  const unsigned int* h = hist + (size_t)seg*CH*NB;
  float carryN = 0.f, carryF = 0.f, lsum = 0.f;
  for (int it = 0; it < NB/64; ++it) {
    int bkt = NB - 1 - (it*64 + lane);   // descending error order
    unsigned int nlo = 0, nhi = 0;
    #pragma unroll
    for (int q = 0; q < CH; ++q) {
      unsigned int c = h[q*NB + bkt];
      nlo += c & 0xffffu; nhi += c >> 16;
    }
    float nb = (float)nlo, fb = (float)nhi;
    float sn = nb, sf = fb;
    #pragma unroll
    for (int off = 1; off < 64; off <<= 1) {
      float tn = __shfl_up(sn, off);
      float tf = __shfl_up(sf, off);
      if (lane >= off) { sn += tn; sf += tf; }
    }
    float Nb = carryN + sn - nb;        // exclusive prefix
    float Fb = carryF + sf - fb;
    if (nlo) {
      float e  = ((float)bkt + 0.5f) * (2.0f/(float)NB);
      float j0 = 1.f - (gts - Fb) / (gts + Nb - Fb);
      float N1 = Nb + nb, F1 = Fb + fb;
      float j1 = 1.f - (gts - F1) / (gts + N1 - F1);
      lsum += e * (j1 - j0);
    }
    carryN += __shfl(sn, 63);
    carryF += __shfl(sf, 63);
  }
  #pragma unroll
  for (int off = 32; off; off >>= 1) lsum += __shfl_down(lsum, off);
  if (lane == 0) instl[seg] = lsum;
}

// ---------------- kernel 5: vreduce + combine ------------------------------
__global__ void __launch_bounds__(256) k_final(
    const float* __restrict__ partial_v, const float* __restrict__ sums,
    const float* __restrict__ instl, const float* __restrict__ seedbg,
    float* __restrict__ out) {
  __shared__ float vsum[256];           // [b][k][comp] reduced over ch
  const int tid = threadIdx.x;
  {
    const int b = tid >> 5, k = (tid & 31) >> 1, comp = tid & 1;
    const float* pv = partial_v + (((size_t)b*KK + k)*CH)*2 + comp;
    float a = 0.f;
    #pragma unroll
    for (int ch = 0; ch < CH; ++ch) a += pv[ch*2];
    vsum[tid] = a;
  }
  __syncthreads();
  float myv = 0.f;
  if (tid < BB) {
    int b = tid;
    float obj = 0.f, il = 0.f, vr = 0.f, sl = 0.f;
    for (int k = 0; k < KK; ++k) {
      float cnt = sums[(b*KK + k)*4];
      if (cnt > 0.f) {
        obj += 1.f;
        il  += instl[b*KK + k];
        vr  += vsum[b*32 + k*2 + 0] / cnt;   // var/(N_SIGMA*safe), safe==cnt
        sl  += vsum[b*32 + k*2 + 1];         // FG_W == 1
      }
    }
    float so = fmaxf(obj, 1.f);
    myv = il/so + 10.f*vr/so + (seedbg[b] + sl)/(float)NPIX;
  }
  #pragma unroll
  for (int off = 4; off; off >>= 1) myv += __shfl_down(myv, off);
  if (tid == 0) out[0] = myv * (1.f/(float)BB);
}

extern "C" void kernel_launch(void* const* d_in, const int* in_sizes, int n_in,
                              void* d_out, int out_size, void* d_ws, size_t ws_size,
                              hipStream_t stream) {
  const float* pred = (const float*)d_in[0];
  const int*   inst = (const int*)d_in[1];
  const int*   lab  = (const int*)d_in[2];
  float* out = (float*)d_out;

  // scalar region [0, 8192): all fully overwritten every call (no memset).
  float* sums   = (float*)d_ws;                          // 512 f32 @ 0
  float* seedbg = (float*)((char*)d_ws + 2048);          // 8 f32
  float* der    = (float*)((char*)d_ws + 2112);          // 128*8 f32
  float* instl  = (float*)((char*)d_ws + 6208);          // 128 f32
  // hist: 128 segs * 64 ch * 192 * 4B = 6,291,456 B @ [8192, 6299648)
  unsigned int* hist = (unsigned int*)((char*)d_ws + 8192);
  float* partial_v = (float*)((char*)d_ws + 6299648);    // 128*64*2 f32 (64KB)
  float* partial_s = (float*)((char*)d_ws + 6365184);    // 8*64*256 f32 (512KB)
  float* partial_b = (float*)((char*)d_ws + 6889472);    // 2048 f32 (8KB)
  // total within proven 8,396,800 budget

  k_sums   <<<BB*256, 256, 0, stream>>>(pred, inst, lab, partial_s, partial_b);
  k_reduce <<<BB, 256, 0, stream>>>(partial_s, partial_b, sums, seedbg, der);
  k_histvar<<<BB*KG*CH, 256, 0, stream>>>(pred, inst, der, hist, partial_v);
  k_lovasz <<<BB*KK, 64, 0, stream>>>(hist, sums, instl);
  k_final  <<<1, 256, 0, stream>>>(partial_v, sums, instl, seedbg, out);
}

// Round 15
// 90.271 us; speedup vs baseline: 1.2360x; 1.0393x over previous
//
#include <hip/hip_runtime.h>

#define HH 512
#define WW 512
#define NPIX (HH*WW)
#define KK 16
#define BB 8
#define NB 192   // lovasz error histogram buckets (%64==0)
#define CHH 256  // pixel chunks per image (1024 px each)

__device__ __forceinline__ float fast_rcp(float x){ return __builtin_amdgcn_rcpf(x); }
__device__ __forceinline__ float fast_tanh(float x){
  x = fminf(fmaxf(x, -15.f), 15.f);
  float t = __expf(2.f*x);
  return (t-1.f)*fast_rcp(t+1.f);
}
__device__ __forceinline__ float fast_sigmoid(float x){
  x = fminf(fmaxf(x, -30.f), 30.f);
  return fast_rcp(1.f+__expf(-x));
}

// ---------------- kernel 1: mask sums (5 comps) + bg seed, zero atomics ----
// grid 2048: b = bid&7 (XCD-affine), ch = bid>>3; 1024 px/block, 4 px/lane.
// comps per k: cnt, Σx, Σy, Σσ, Σσ²  (Σσ² enables var = Σσ² − cnt·s̄²,
// removing the var pass from the hist kernel entirely).
__global__ void __launch_bounds__(256) k_sums(
    const float* __restrict__ pred, const int* __restrict__ inst,
    const int* __restrict__ lab, float* __restrict__ partial_s /*[B][80][256]*/,
    float* __restrict__ partial_b /*[2048]*/) {
  const int bid = blockIdx.x;
  const int b  = bid & 7;
  const int ch = bid >> 3;
  const int tid = threadIdx.x;
  const int wave = tid >> 6, lane = tid & 63;
  __shared__ float lred[KK][16][5];   // [k][group][comp], 5KB
  __shared__ float lbg[4];
  const float inv = 1.f/511.f;
  const float* ps = pred + (size_t)b*4*NPIX + 2*NPIX;  // sigma channel
  const float* pd = ps + NPIX;                          // seed channel
  const int*   ib = inst + (size_t)b*NPIX;
  const int*   lb = lab  + (size_t)b*NPIX;
  const int p = ch*1024 + tid*4;
  int4   iv = *(const int4*)(ib + p);
  int4   lv = *(const int4*)(lb + p);
  float4 sv = *(const float4*)(ps + p);
  float4 dv = *(const float4*)(pd + p);
  const float ym  = (float)(p >> 9) * inv;    // lane's 4 px share a row
  const float xm0 = (float)(p & (WW-1)) * inv;
  int   ida[4] = {iv.x, iv.y, iv.z, iv.w};
  int   laa[4] = {lv.x, lv.y, lv.z, lv.w};
  float sga[4] = {sv.x, sv.y, sv.z, sv.w};
  float sda[4] = {dv.x, dv.y, dv.z, dv.w};
  float xja[4] = {xm0, xm0+inv, xm0+2.f*inv, xm0+3.f*inv};
  float sg2[4] = {sga[0]*sga[0], sga[1]*sga[1], sga[2]*sga[2], sga[3]*sga[3]};

  // bg seed: register + shfl reduce
  float sbg = 0.f;
  #pragma unroll
  for (int j = 0; j < 4; ++j)
    if (laa[j] == 0) { float sd = fast_sigmoid(sda[j]); sbg += sd*sd; }
  #pragma unroll
  for (int off = 32; off; off >>= 1) sbg += __shfl_down(sbg, off);
  if (lane == 0) lbg[wave] = sbg;

  // per-instance 5-comp condense -> 16-lane-group butterfly -> LDS slot
  #pragma unroll
  for (int k = 0; k < KK; ++k) {
    float c = 0.f, sx = 0.f, ss = 0.f, sq = 0.f;
    #pragma unroll
    for (int j = 0; j < 4; ++j) {
      float m = (ida[j] == k+1) ? 1.f : 0.f;
      c  += m;
      sx = fmaf(m, xja[j], sx);
      ss = fmaf(m, sga[j], ss);
      sq = fmaf(m, sg2[j], sq);
    }
    float sy = c * ym;
    #pragma unroll
    for (int off = 1; off < 16; off <<= 1) {
      c  += __shfl_xor(c,  off);
      sx += __shfl_xor(sx, off);
      sy += __shfl_xor(sy, off);
      ss += __shfl_xor(ss, off);
      sq += __shfl_xor(sq, off);
    }
    if ((lane & 15) == 0) {
      int g = wave*4 + (lane >> 4);
      lred[k][g][0] = c;  lred[k][g][1] = sx; lred[k][g][2] = sy;
      lred[k][g][3] = ss; lred[k][g][4] = sq;
    }
  }
  __syncthreads();
  if (tid < KK) {          // 16 threads x 5 comps, fold 16 groups each
    #pragma unroll
    for (int comp = 0; comp < 5; ++comp) {
      float a = 0.f;
      #pragma unroll
      for (int g = 0; g < 16; ++g) a += lred[tid][g][comp];
      partial_s[((size_t)b*80 + tid*5 + comp)*256 + ch] = a;
    }
  }
  if (tid == 64) partial_b[bid] = lbg[0] + lbg[1] + lbg[2] + lbg[3];
}

// ---------------- kernel 2: reduce partials -> der, seedbg ----------------
// grid 8 x 256. der[seg][8] = {cx, cy, sexp, act, pad, cnt, var, pad}
__global__ void __launch_bounds__(256) k_reduce(
    const float* __restrict__ partial_s, const float* __restrict__ partial_b,
    float* __restrict__ seedbg, float* __restrict__ der) {
  const int b = blockIdx.x;
  const int tid = threadIdx.x;
  const int w = tid >> 6, l = tid & 63;
  __shared__ float lsum[80];
  __shared__ float lsb[4];
  #pragma unroll
  for (int i = 0; i < 20; ++i) {
    int s = w + 4*i;
    const float* row = partial_s + ((size_t)b*80 + s)*256;
    float a = row[l] + row[l+64] + row[l+128] + row[l+192];
    #pragma unroll
    for (int off = 32; off; off >>= 1) a += __shfl_down(a, off);
    if (l == 0) lsum[s] = a;
  }
  {
    float a = partial_b[(size_t)tid*8 + b];   // ch = tid in [0,256)
    #pragma unroll
    for (int off = 32; off; off >>= 1) a += __shfl_down(a, off);
    if (l == 0) lsb[w] = a;
  }
  __syncthreads();
  if (tid == 64) seedbg[b] = lsb[0] + lsb[1] + lsb[2] + lsb[3];
  if (tid < KK) {
    float cnt  = lsum[tid*5+0];
    float safe = fmaxf(cnt, 1.f);
    float rs   = fast_rcp(safe);
    float cx = lsum[tid*5+1]*rs;
    float cy = lsum[tid*5+2]*rs;
    float sb = lsum[tid*5+3]*rs;
    float sq = lsum[tid*5+4];
    float* dd = der + (b*KK + tid)*8;
    dd[0] = cx; dd[1] = cy;
    dd[2] = __expf(10.f*sb);
    dd[3] = (cnt > 0.f) ? 1.f : 0.f;
    dd[4] = sb;
    dd[5] = cnt;
    dd[6] = sq - cnt*sb*sb;      // = Σ(σ−s̄)² over mask
  }
}

// ---------------- kernel 3: unified 16-instance hist + fg seed loss -------
// grid 2048: b = bid&7, ch = bid>>3; 1024 px/block. LDS hist 16x192 (12KB).
// Each pixel read ONCE, tanh ONCE, 16 DOKs. Seed loss is a GLOBAL sum over
// fg pixels (every fg pixel's instance is present), so no per-k scatter.
__global__ void __launch_bounds__(256, 4) k_hist(
    const float* __restrict__ pred, const int* __restrict__ inst,
    const float* __restrict__ der, unsigned int* __restrict__ hist,
    float* __restrict__ partial_v /*[2048]*/) {
  const int bid = blockIdx.x;
  const int b  = bid & 7;
  const int ch = bid >> 3;
  const int tid = threadIdx.x;
  __shared__ unsigned int lh[KK][NB];
  __shared__ float sder[KK][4];   // cx, cy, sexp, act
  __shared__ float lsl[4];
  if (tid < KK) {
    const float* dd = der + (b*KK + tid)*8;
    sder[tid][0] = dd[0]; sder[tid][1] = dd[1];
    sder[tid][2] = dd[2]; sder[tid][3] = dd[3];
  }
  for (int i = tid; i < KK*NB; i += 256) ((unsigned int*)lh)[i] = 0u;
  __syncthreads();
  float cxa[KK], cya[KK], sea[KK]; bool aca[KK];
  #pragma unroll
  for (int k = 0; k < KK; ++k) {
    cxa[k] = sder[k][0]; cya[k] = sder[k][1];
    sea[k] = sder[k][2]; aca[k] = sder[k][3] > 0.f;
  }
  const float inv = 1.f/511.f;
  const float* pbx = pred + (size_t)b*4*NPIX;
  const float* pby = pbx + NPIX;
  const float* pbd = pbx + 3*NPIX;   // seed channel
  const int*   ib  = inst + (size_t)b*NPIX;
  const int p = ch*1024 + tid*4;
  float4 px = *(const float4*)(pbx + p);
  float4 py = *(const float4*)(pby + p);
  int4   iv = *(const int4*)(ib + p);
  float4 dv = *(const float4*)(pbd + p);
  const float ym  = (float)(p >> 9) * inv;
  const float xm0 = (float)(p & (WW-1)) * inv;
  float pxa[4] = {px.x, px.y, px.z, px.w};
  float pya[4] = {py.x, py.y, py.z, py.w};
  int   ida[4] = {iv.x, iv.y, iv.z, iv.w};
  float sda[4] = {dv.x, dv.y, dv.z, dv.w};
  float sloss = 0.f;
  #pragma unroll
  for (int j = 0; j < 4; ++j) {
    float sex = fast_tanh(pxa[j]) + xm0 + (float)j*inv;
    float sey = fast_tanh(pya[j]) + ym;
    int id = ida[j];
    float down = 0.f;
    #pragma unroll
    for (int k = 0; k < KK; ++k) {
      if (aca[k]) {
        float dx = sex - cxa[k], dy = sey - cya[k];
        float d = __expf(-sea[k]*(dx*dx + dy*dy));
        bool fg = (id == k+1);
        float u  = fg ? (1.f - d) : d;
        int bkt = (int)(u * (float)NB);
        bkt = bkt < (NB-1) ? bkt : (NB-1);
        atomicAdd(&lh[k][bkt], fg ? 0x10001u : 1u);
        down = fg ? d : down;
      }
    }
    if (id >= 1) {
      float dsee = fast_sigmoid(sda[j]) - down;
      sloss = fmaf(dsee, dsee, sloss);
    }
  }
  __syncthreads();
  // flush 16 hists -> disjoint global regions (coalesced stores)
  #pragma unroll
  for (int k = 0; k < KK; ++k) {
    unsigned int* gh = hist + ((size_t)(b*KK + k)*CHH + ch)*NB;
    if (tid < NB) gh[tid] = lh[k][tid];
  }
  // block-reduce seed loss -> 1 float per block
  #pragma unroll
  for (int off = 32; off; off >>= 1) sloss += __shfl_down(sloss, off);
  if ((tid & 63) == 0) lsl[tid >> 6] = sloss;
  __syncthreads();
  if (tid == 0) partial_v[bid] = lsl[0] + lsl[1] + lsl[2] + lsl[3];
}

// ---------------- kernel 4: lovasz, 2-phase (collapse + scan) -------------
__global__ void __launch_bounds__(256) k_lovasz(
    const unsigned int* __restrict__ hist,
    const float* __restrict__ der, float* __restrict__ instl) {
  const int seg = blockIdx.x;           // b*K + k
  const int tid = threadIdx.x;
  __shared__ float nbL[NB], fbL[NB];
  const float gts = der[seg*8 + 5];
  const unsigned int* h = hist + (size_t)seg*CHH*NB;
  if (tid < NB) {
    unsigned int nlo = 0, nhi = 0;
    #pragma unroll 8
    for (int c = 0; c < CHH; ++c) {
      unsigned int v = h[(size_t)c*NB + tid];
      nlo += v & 0xffffu; nhi += v >> 16;
    }
    nbL[tid] = (float)nlo; fbL[tid] = (float)nhi;
  }
  __syncthreads();
  if (tid >= 64) return;
  const int lane = tid;
  if (gts <= 0.f) { if (lane == 0) instl[seg] = 0.f; return; }
  float carryN = 0.f, carryF = 0.f, lsum = 0.f;
  #pragma unroll
  for (int it = 0; it < NB/64; ++it) {
    int bkt = NB - 1 - (it*64 + lane);   // descending error order
    float nb = nbL[bkt], fb = fbL[bkt];
    float sn = nb, sf = fb;
    #pragma unroll
    for (int off = 1; off < 64; off <<= 1) {
      float tn = __shfl_up(sn, off);
      float tf = __shfl_up(sf, off);
      if (lane >= off) { sn += tn; sf += tf; }
    }
    float Nb = carryN + sn - nb;        // exclusive prefix
    float Fb = carryF + sf - fb;
    if (nb > 0.f) {
      float e  = ((float)bkt + 0.5f) * (2.0f/(float)NB);
      float j0 = 1.f - (gts - Fb) / (gts + Nb - Fb);
      float N1 = Nb + nb, F1 = Fb + fb;
      float j1 = 1.f - (gts - F1) / (gts + N1 - F1);
      lsum += e * (j1 - j0);
    }
    carryN += __shfl(sn, 63);
    carryF += __shfl(sf, 63);
  }
  #pragma unroll
  for (int off = 32; off; off >>= 1) lsum += __shfl_down(lsum, off);
  if (lane == 0) instl[seg] = lsum;
}

// ---------------- kernel 5: combine ---------------------------------------
__global__ void __launch_bounds__(256) k_final(
    const float* __restrict__ partial_v, const float* __restrict__ der,
    const float* __restrict__ instl, const float* __restrict__ seedbg,
    float* __restrict__ out) {
  __shared__ float vtmp[256];
  const int tid = threadIdx.x;
  {
    const int b8 = tid >> 5, j = tid & 31;
    float a = 0.f;
    #pragma unroll
    for (int i = 0; i < 8; ++i) a += partial_v[(size_t)(j + 32*i)*8 + b8];
    vtmp[tid] = a;
  }
  __syncthreads();
  float myv = 0.f;
  if (tid < BB) {
    int b = tid;
    float svl = 0.f;
    #pragma unroll
    for (int j = 0; j < 32; ++j) svl += vtmp[b*32 + j];
    float obj = 0.f, il = 0.f, vr = 0.f;
    for (int k = 0; k < KK; ++k) {
      int seg = b*KK + k;
      float cnt = der[seg*8 + 5];
      if (cnt > 0.f) {
        obj += 1.f;
        il  += instl[seg];
        vr  += der[seg*8 + 6] / cnt;   // var/(N_SIGMA*safe), safe==cnt
      }
    }
    float so = fmaxf(obj, 1.f);
    myv = il/so + 10.f*vr/so + (seedbg[b] + svl)/(float)NPIX;
  }
  #pragma unroll
  for (int off = 4; off; off >>= 1) myv += __shfl_down(myv, off);
  if (tid == 0) out[0] = myv * (1.f/(float)BB);
}

extern "C" void kernel_launch(void* const* d_in, const int* in_sizes, int n_in,
                              void* d_out, int out_size, void* d_ws, size_t ws_size,
                              hipStream_t stream) {
  const float* pred = (const float*)d_in[0];
  const int*   inst = (const int*)d_in[1];
  const int*   lab  = (const int*)d_in[2];
  float* out = (float*)d_out;

  // ws is 256 MiB (measured via harness poison fill). Layout (~25.8 MB used),
  // every byte below is fully overwritten each call (no memset needed):
  float* der       = (float*)d_ws;                         // 128*8 f32 @ 0
  float* seedbg    = (float*)((char*)d_ws + 4096);         // 8 f32
  float* instl     = (float*)((char*)d_ws + 4160);         // 128 f32
  float* partial_b = (float*)((char*)d_ws + 8192);         // 2048 f32
  float* partial_v = (float*)((char*)d_ws + 16384);        // 2048 f32
  float* partial_s = (float*)((char*)d_ws + 24576);        // 8*80*256 f32 (640KB)
  unsigned int* hist = (unsigned int*)((char*)d_ws + 679936); // 128*256*192*4 = 24MB

  k_sums  <<<BB*CHH, 256, 0, stream>>>(pred, inst, lab, partial_s, partial_b);
  k_reduce<<<BB, 256, 0, stream>>>(partial_s, partial_b, seedbg, der);
  k_hist  <<<BB*CHH, 256, 0, stream>>>(pred, inst, der, hist, partial_v);
  k_lovasz<<<BB*KK, 256, 0, stream>>>(hist, der, instl);
  k_final <<<1, 256, 0, stream>>>(partial_v, der, instl, seedbg, out);
}

// Round 16
// 66.966 us; speedup vs baseline: 1.6662x; 1.3480x over previous
//
#include <hip/hip_runtime.h>

#define HH 512
#define WW 512
#define NPIX (HH*WW)
#define KK 16
#define BB 8
#define NB 192   // lovasz error histogram buckets (%64==0)
#define CHV 64   // pixel chunks per image in k_hist (4096 px each)

__device__ __forceinline__ float fast_rcp(float x){ return __builtin_amdgcn_rcpf(x); }
__device__ __forceinline__ float fast_tanh(float x){
  x = fminf(fmaxf(x, -15.f), 15.f);
  float t = __expf(2.f*x);
  return (t-1.f)*fast_rcp(t+1.f);
}
__device__ __forceinline__ float fast_sigmoid(float x){
  x = fminf(fmaxf(x, -30.f), 30.f);
  return fast_rcp(1.f+__expf(-x));
}

// DPP 16-lane-row sum: after this, lane 15 (mod 16) holds the row sum.
// v_add via DPP row_shr runs on the VALU pipe (per-SIMD), NOT the per-CU
// LDS pipe that ds_swizzle (__shfl_xor) uses — that pipe was the 31us.
__device__ __forceinline__ float dpp_row_sum16(float v){
  v += __int_as_float(__builtin_amdgcn_update_dpp(0, __float_as_int(v), 0x111, 0xf, 0xf, true)); // row_shr:1
  v += __int_as_float(__builtin_amdgcn_update_dpp(0, __float_as_int(v), 0x112, 0xf, 0xf, true)); // row_shr:2
  v += __int_as_float(__builtin_amdgcn_update_dpp(0, __float_as_int(v), 0x114, 0xf, 0xf, true)); // row_shr:4
  v += __int_as_float(__builtin_amdgcn_update_dpp(0, __float_as_int(v), 0x118, 0xf, 0xf, true)); // row_shr:8
  return v;
}

// ---------------- kernel 1: mask sums (5 comps) + bg seed ------------------
// grid 2048: b = bid&7 (XCD-affine), ch = bid>>3; 1024 px/block, 4 px/lane.
__global__ void __launch_bounds__(256) k_sums(
    const float* __restrict__ pred, const int* __restrict__ inst,
    const int* __restrict__ lab, float* __restrict__ partial_s /*[B][80][256]*/,
    float* __restrict__ partial_b /*[2048]*/) {
  const int bid = blockIdx.x;
  const int b  = bid & 7;
  const int ch = bid >> 3;
  const int tid = threadIdx.x;
  const int wave = tid >> 6, lane = tid & 63;
  __shared__ float lred[KK][16][5];   // [k][group][comp], 5KB
  __shared__ float lbg[4];
  const float inv = 1.f/511.f;
  const float* ps = pred + (size_t)b*4*NPIX + 2*NPIX;  // sigma channel
  const float* pd = ps + NPIX;                          // seed channel
  const int*   ib = inst + (size_t)b*NPIX;
  const int*   lb = lab  + (size_t)b*NPIX;
  const int p = ch*1024 + tid*4;
  int4   iv = *(const int4*)(ib + p);
  int4   lv = *(const int4*)(lb + p);
  float4 sv = *(const float4*)(ps + p);
  float4 dv = *(const float4*)(pd + p);
  const float ym  = (float)(p >> 9) * inv;    // lane's 4 px share a row
  const float xm0 = (float)(p & (WW-1)) * inv;
  int   ida[4] = {iv.x, iv.y, iv.z, iv.w};
  int   laa[4] = {lv.x, lv.y, lv.z, lv.w};
  float sga[4] = {sv.x, sv.y, sv.z, sv.w};
  float sda[4] = {dv.x, dv.y, dv.z, dv.w};
  float xja[4] = {xm0, xm0+inv, xm0+2.f*inv, xm0+3.f*inv};
  float sg2[4] = {sga[0]*sga[0], sga[1]*sga[1], sga[2]*sga[2], sga[3]*sga[3]};

  // bg seed: register + shfl reduce (few ops, not on the critical path)
  float sbg = 0.f;
  #pragma unroll
  for (int j = 0; j < 4; ++j)
    if (laa[j] == 0) { float sd = fast_sigmoid(sda[j]); sbg += sd*sd; }
  #pragma unroll
  for (int off = 32; off; off >>= 1) sbg += __shfl_down(sbg, off);
  if (lane == 0) lbg[wave] = sbg;

  // per-instance 5-comp condense -> DPP row-sum -> lane-15 leaders to LDS
  #pragma unroll
  for (int k = 0; k < KK; ++k) {
    float c = 0.f, sx = 0.f, ss = 0.f, sq = 0.f;
    #pragma unroll
    for (int j = 0; j < 4; ++j) {
      float m = (ida[j] == k+1) ? 1.f : 0.f;
      c  += m;
      sx = fmaf(m, xja[j], sx);
      ss = fmaf(m, sga[j], ss);
      sq = fmaf(m, sg2[j], sq);
    }
    float sy = c * ym;
    c  = dpp_row_sum16(c);
    sx = dpp_row_sum16(sx);
    sy = dpp_row_sum16(sy);
    ss = dpp_row_sum16(ss);
    sq = dpp_row_sum16(sq);
    if ((lane & 15) == 15) {
      int g = wave*4 + (lane >> 4);
      lred[k][g][0] = c;  lred[k][g][1] = sx; lred[k][g][2] = sy;
      lred[k][g][3] = ss; lred[k][g][4] = sq;
    }
  }
  __syncthreads();
  if (tid < KK) {          // 16 threads x 5 comps, fold 16 groups each
    #pragma unroll
    for (int comp = 0; comp < 5; ++comp) {
      float a = 0.f;
      #pragma unroll
      for (int g = 0; g < 16; ++g) a += lred[tid][g][comp];
      partial_s[((size_t)b*80 + tid*5 + comp)*256 + ch] = a;
    }
  }
  if (tid == 64) partial_b[bid] = lbg[0] + lbg[1] + lbg[2] + lbg[3];
}

// ---------------- kernel 2: reduce partials -> der, seedbg ----------------
// grid 8 x 256. der[seg][8] = {cx, cy, sexp, act, sbar, cnt, var, pad}
__global__ void __launch_bounds__(256) k_reduce(
    const float* __restrict__ partial_s, const float* __restrict__ partial_b,
    float* __restrict__ seedbg, float* __restrict__ der) {
  const int b = blockIdx.x;
  const int tid = threadIdx.x;
  const int w = tid >> 6, l = tid & 63;
  __shared__ float lsum[80];
  __shared__ float lsb[4];
  #pragma unroll
  for (int i = 0; i < 20; ++i) {
    int s = w + 4*i;
    const float* row = partial_s + ((size_t)b*80 + s)*256;
    float a = row[l] + row[l+64] + row[l+128] + row[l+192];
    #pragma unroll
    for (int off = 32; off; off >>= 1) a += __shfl_down(a, off);
    if (l == 0) lsum[s] = a;
  }
  {
    float a = partial_b[(size_t)tid*8 + b];   // ch = tid in [0,256)
    #pragma unroll
    for (int off = 32; off; off >>= 1) a += __shfl_down(a, off);
    if (l == 0) lsb[w] = a;
  }
  __syncthreads();
  if (tid == 64) seedbg[b] = lsb[0] + lsb[1] + lsb[2] + lsb[3];
  if (tid < KK) {
    float cnt  = lsum[tid*5+0];
    float safe = fmaxf(cnt, 1.f);
    float rs   = fast_rcp(safe);
    float cx = lsum[tid*5+1]*rs;
    float cy = lsum[tid*5+2]*rs;
    float sb = lsum[tid*5+3]*rs;
    float sq = lsum[tid*5+4];
    float* dd = der + (b*KK + tid)*8;
    dd[0] = cx; dd[1] = cy;
    dd[2] = __expf(10.f*sb);
    dd[3] = (cnt > 0.f) ? 1.f : 0.f;
    dd[4] = sb;
    dd[5] = cnt;
    dd[6] = sq - cnt*sb*sb;      // = Σ(σ−s̄)² over mask
  }
}

// ---------------- kernel 3: unified 16-instance hist + fg seed loss -------
// grid 512: b = bid&7, ch = bid>>3 in [0,64); 4096 px/block (4 batches).
// LDS hist 16x192 (12KB); pixel read once, tanh once, 16 DOKs.
__global__ void __launch_bounds__(256) k_hist(
    const float* __restrict__ pred, const int* __restrict__ inst,
    const float* __restrict__ der, unsigned int* __restrict__ hist,
    float* __restrict__ partial_v /*[512]*/) {
  const int bid = blockIdx.x;
  const int b  = bid & 7;
  const int ch = bid >> 3;
  const int tid = threadIdx.x;
  __shared__ unsigned int lh[KK][NB];
  __shared__ float sder[KK][4];   // cx, cy, sexp, act
  __shared__ float lsl[4];
  if (tid < KK) {
    const float* dd = der + (b*KK + tid)*8;
    sder[tid][0] = dd[0]; sder[tid][1] = dd[1];
    sder[tid][2] = dd[2]; sder[tid][3] = dd[3];
  }
  for (int i = tid; i < KK*NB; i += 256) ((unsigned int*)lh)[i] = 0u;
  __syncthreads();
  float cxa[KK], cya[KK], sea[KK]; bool aca[KK];
  #pragma unroll
  for (int k = 0; k < KK; ++k) {
    cxa[k] = sder[k][0]; cya[k] = sder[k][1];
    sea[k] = sder[k][2]; aca[k] = sder[k][3] > 0.f;
  }
  const float inv = 1.f/511.f;
  const float* pbx = pred + (size_t)b*4*NPIX;
  const float* pby = pbx + NPIX;
  const float* pbd = pbx + 3*NPIX;   // seed channel
  const int*   ib  = inst + (size_t)b*NPIX;
  const int base = ch*4096;
  float sloss = 0.f;
  #pragma unroll
  for (int it = 0; it < 4; ++it) {
    const int p = base + it*1024 + tid*4;
    float4 px = *(const float4*)(pbx + p);
    float4 py = *(const float4*)(pby + p);
    int4   iv = *(const int4*)(ib + p);
    float4 dv = *(const float4*)(pbd + p);
    const float ym  = (float)(p >> 9) * inv;
    const float xm0 = (float)(p & (WW-1)) * inv;
    float pxa[4] = {px.x, px.y, px.z, px.w};
    float pya[4] = {py.x, py.y, py.z, py.w};
    int   ida[4] = {iv.x, iv.y, iv.z, iv.w};
    float sda[4] = {dv.x, dv.y, dv.z, dv.w};
    #pragma unroll
    for (int j = 0; j < 4; ++j) {
      float sex = fast_tanh(pxa[j]) + xm0 + (float)j*inv;
      float sey = fast_tanh(pya[j]) + ym;
      int id = ida[j];
      float down = 0.f;
      #pragma unroll
      for (int k = 0; k < KK; ++k) {
        if (aca[k]) {
          float dx = sex - cxa[k], dy = sey - cya[k];
          float d = __expf(-sea[k]*(dx*dx + dy*dy));
          bool fg = (id == k+1);
          float u  = fg ? (1.f - d) : d;
          int bkt = (int)(u * (float)NB);
          bkt = bkt < (NB-1) ? bkt : (NB-1);
          atomicAdd(&lh[k][bkt], fg ? 0x10001u : 1u);
          down = fg ? d : down;
        }
      }
      if (id >= 1) {
        float dsee = fast_sigmoid(sda[j]) - down;
        sloss = fmaf(dsee, dsee, sloss);
      }
    }
  }
  __syncthreads();
  // flush 16 hists -> disjoint global regions
  #pragma unroll
  for (int k = 0; k < KK; ++k) {
    unsigned int* gh = hist + ((size_t)(b*KK + k)*CHV + ch)*NB;
    if (tid < NB) gh[tid] = lh[k][tid];
  }
  // block-reduce seed loss -> 1 float per block
  #pragma unroll
  for (int off = 32; off; off >>= 1) sloss += __shfl_down(sloss, off);
  if ((tid & 63) == 0) lsl[tid >> 6] = sloss;
  __syncthreads();
  if (tid == 0) partial_v[bid] = lsl[0] + lsl[1] + lsl[2] + lsl[3];
}

// ---------------- kernel 4: lovasz, 2-phase (collapse + scan) -------------
__global__ void __launch_bounds__(256) k_lovasz(
    const unsigned int* __restrict__ hist,
    const float* __restrict__ der, float* __restrict__ instl) {
  const int seg = blockIdx.x;           // b*K + k
  const int tid = threadIdx.x;
  __shared__ float nbL[NB], fbL[NB];
  const float gts = der[seg*8 + 5];
  const unsigned int* h = hist + (size_t)seg*CHV*NB;
  if (tid < NB) {
    unsigned int nlo = 0, nhi = 0;
    #pragma unroll 8
    for (int c = 0; c < CHV; ++c) {
      unsigned int v = h[(size_t)c*NB + tid];
      nlo += v & 0xffffu; nhi += v >> 16;
    }
    nbL[tid] = (float)nlo; fbL[tid] = (float)nhi;
  }
  __syncthreads();
  if (tid >= 64) return;
  const int lane = tid;
  if (gts <= 0.f) { if (lane == 0) instl[seg] = 0.f; return; }
  float carryN = 0.f, carryF = 0.f, lsum = 0.f;
  #pragma unroll
  for (int it = 0; it < NB/64; ++it) {
    int bkt = NB - 1 - (it*64 + lane);   // descending error order
    float nb = nbL[bkt], fb = fbL[bkt];
    float sn = nb, sf = fb;
    #pragma unroll
    for (int off = 1; off < 64; off <<= 1) {
      float tn = __shfl_up(sn, off);
      float tf = __shfl_up(sf, off);
      if (lane >= off) { sn += tn; sf += tf; }
    }
    float Nb = carryN + sn - nb;        // exclusive prefix
    float Fb = carryF + sf - fb;
    if (nb > 0.f) {
      float e  = ((float)bkt + 0.5f) * (2.0f/(float)NB);
      float j0 = 1.f - (gts - Fb) / (gts + Nb - Fb);
      float N1 = Nb + nb, F1 = Fb + fb;
      float j1 = 1.f - (gts - F1) / (gts + N1 - F1);
      lsum += e * (j1 - j0);
    }
    carryN += __shfl(sn, 63);
    carryF += __shfl(sf, 63);
  }
  #pragma unroll
  for (int off = 32; off; off >>= 1) lsum += __shfl_down(lsum, off);
  if (lane == 0) instl[seg] = lsum;
}

// ---------------- kernel 5: combine ---------------------------------------
__global__ void __launch_bounds__(256) k_final(
    const float* __restrict__ partial_v, const float* __restrict__ der,
    const float* __restrict__ instl, const float* __restrict__ seedbg,
    float* __restrict__ out) {
  __shared__ float vtmp[256];
  const int tid = threadIdx.x;
  {
    const int b8 = tid >> 5, j = tid & 31;
    float a = 0.f;
    #pragma unroll
    for (int i = 0; i < 2; ++i) a += partial_v[(size_t)(j + 32*i)*8 + b8];
    vtmp[tid] = a;
  }
  __syncthreads();
  float myv = 0.f;
  if (tid < BB) {
    int b = tid;
    float svl = 0.f;
    #pragma unroll
    for (int j = 0; j < 32; ++j) svl += vtmp[b*32 + j];
    float obj = 0.f, il = 0.f, vr = 0.f;
    for (int k = 0; k < KK; ++k) {
      int seg = b*KK + k;
      float cnt = der[seg*8 + 5];
      if (cnt > 0.f) {
        obj += 1.f;
        il  += instl[seg];
        vr  += der[seg*8 + 6] / cnt;   // var/(N_SIGMA*safe), safe==cnt
      }
    }
    float so = fmaxf(obj, 1.f);
    myv = il/so + 10.f*vr/so + (seedbg[b] + svl)/(float)NPIX;
  }
  #pragma unroll
  for (int off = 4; off; off >>= 1) myv += __shfl_down(myv, off);
  if (tid == 0) out[0] = myv * (1.f/(float)BB);
}

extern "C" void kernel_launch(void* const* d_in, const int* in_sizes, int n_in,
                              void* d_out, int out_size, void* d_ws, size_t ws_size,
                              hipStream_t stream) {
  const float* pred = (const float*)d_in[0];
  const int*   inst = (const int*)d_in[1];
  const int*   lab  = (const int*)d_in[2];
  float* out = (float*)d_out;

  // ws layout (~7 MB used of 256 MiB); all fully overwritten every call.
  float* der       = (float*)d_ws;                         // 128*8 f32 @ 0
  float* seedbg    = (float*)((char*)d_ws + 4096);         // 8 f32
  float* instl     = (float*)((char*)d_ws + 4160);         // 128 f32
  float* partial_b = (float*)((char*)d_ws + 8192);         // 2048 f32
  float* partial_v = (float*)((char*)d_ws + 16384);        // 512 f32
  float* partial_s = (float*)((char*)d_ws + 24576);        // 8*80*256 f32 (640KB)
  unsigned int* hist = (unsigned int*)((char*)d_ws + 679936); // 128*64*192*4 = 6.29MB

  k_sums  <<<BB*256, 256, 0, stream>>>(pred, inst, lab, partial_s, partial_b);
  k_reduce<<<BB, 256, 0, stream>>>(partial_s, partial_b, seedbg, der);
  k_hist  <<<BB*CHV, 256, 0, stream>>>(pred, inst, der, hist, partial_v);
  k_lovasz<<<BB*KK, 256, 0, stream>>>(hist, der, instl);
  k_final <<<1, 256, 0, stream>>>(partial_v, der, instl, seedbg, out);
}

// Round 17
// 66.318 us; speedup vs baseline: 1.6825x; 1.0098x over previous
//
#include <hip/hip_runtime.h>

#define HH 512
#define WW 512
#define NPIX (HH*WW)
#define KK 16
#define BB 8
#define NB 192   // lovasz error histogram buckets (%64==0)
#define NBP 200  // padded LDS hist row (bank stagger: 200%32=8)
#define CHV 128  // pixel chunks per image in k_hist (2048 px each)

__device__ __forceinline__ float fast_rcp(float x){ return __builtin_amdgcn_rcpf(x); }
__device__ __forceinline__ float fast_tanh(float x){
  x = fminf(fmaxf(x, -15.f), 15.f);
  float t = __expf(2.f*x);
  return (t-1.f)*fast_rcp(t+1.f);
}
__device__ __forceinline__ float fast_sigmoid(float x){
  x = fminf(fmaxf(x, -30.f), 30.f);
  return fast_rcp(1.f+__expf(-x));
}

// DPP 16-lane-row sum (VALU pipe, not the per-CU LDS pipe): lane 15 of each
// 16-group holds the sum afterwards.
__device__ __forceinline__ float dpp_row_sum16(float v){
  v += __int_as_float(__builtin_amdgcn_update_dpp(0, __float_as_int(v), 0x111, 0xf, 0xf, true)); // row_shr:1
  v += __int_as_float(__builtin_amdgcn_update_dpp(0, __float_as_int(v), 0x112, 0xf, 0xf, true)); // row_shr:2
  v += __int_as_float(__builtin_amdgcn_update_dpp(0, __float_as_int(v), 0x114, 0xf, 0xf, true)); // row_shr:4
  v += __int_as_float(__builtin_amdgcn_update_dpp(0, __float_as_int(v), 0x118, 0xf, 0xf, true)); // row_shr:8
  return v;
}

// ---------------- kernel 1: mask sums (5 comps) + bg seed ------------------
// grid 2048: b = bid&7 (XCD-affine), ch = bid>>3; 1024 px/block, 4 px/lane.
__global__ void __launch_bounds__(256) k_sums(
    const float* __restrict__ pred, const int* __restrict__ inst,
    const int* __restrict__ lab, float* __restrict__ partial_s /*[B][80][256]*/,
    float* __restrict__ partial_b /*[2048]*/) {
  const int bid = blockIdx.x;
  const int b  = bid & 7;
  const int ch = bid >> 3;
  const int tid = threadIdx.x;
  const int wave = tid >> 6, lane = tid & 63;
  __shared__ float lred[KK][16][5];   // [k][group][comp], 5KB
  __shared__ float lbg[4];
  const float inv = 1.f/511.f;
  const float* ps = pred + (size_t)b*4*NPIX + 2*NPIX;  // sigma channel
  const float* pd = ps + NPIX;                          // seed channel
  const int*   ib = inst + (size_t)b*NPIX;
  const int*   lb = lab  + (size_t)b*NPIX;
  const int p = ch*1024 + tid*4;
  int4   iv = *(const int4*)(ib + p);
  int4   lv = *(const int4*)(lb + p);
  float4 sv = *(const float4*)(ps + p);
  float4 dv = *(const float4*)(pd + p);
  const float ym  = (float)(p >> 9) * inv;    // lane's 4 px share a row
  const float xm0 = (float)(p & (WW-1)) * inv;
  int   ida[4] = {iv.x, iv.y, iv.z, iv.w};
  int   laa[4] = {lv.x, lv.y, lv.z, lv.w};
  float sga[4] = {sv.x, sv.y, sv.z, sv.w};
  float sda[4] = {dv.x, dv.y, dv.z, dv.w};
  float xja[4] = {xm0, xm0+inv, xm0+2.f*inv, xm0+3.f*inv};
  float sg2[4] = {sga[0]*sga[0], sga[1]*sga[1], sga[2]*sga[2], sga[3]*sga[3]};

  // bg seed: register + shfl reduce (few ops)
  float sbg = 0.f;
  #pragma unroll
  for (int j = 0; j < 4; ++j)
    if (laa[j] == 0) { float sd = fast_sigmoid(sda[j]); sbg += sd*sd; }
  #pragma unroll
  for (int off = 32; off; off >>= 1) sbg += __shfl_down(sbg, off);
  if (lane == 0) lbg[wave] = sbg;

  // per-instance 5-comp condense -> DPP row-sum -> lane-15 leaders to LDS
  #pragma unroll
  for (int k = 0; k < KK; ++k) {
    float c = 0.f, sx = 0.f, ss = 0.f, sq = 0.f;
    #pragma unroll
    for (int j = 0; j < 4; ++j) {
      float m = (ida[j] == k+1) ? 1.f : 0.f;
      c  += m;
      sx = fmaf(m, xja[j], sx);
      ss = fmaf(m, sga[j], ss);
      sq = fmaf(m, sg2[j], sq);
    }
    float sy = c * ym;
    c  = dpp_row_sum16(c);
    sx = dpp_row_sum16(sx);
    sy = dpp_row_sum16(sy);
    ss = dpp_row_sum16(ss);
    sq = dpp_row_sum16(sq);
    if ((lane & 15) == 15) {
      int g = wave*4 + (lane >> 4);
      lred[k][g][0] = c;  lred[k][g][1] = sx; lred[k][g][2] = sy;
      lred[k][g][3] = ss; lred[k][g][4] = sq;
    }
  }
  __syncthreads();
  if (tid < KK) {
    #pragma unroll
    for (int comp = 0; comp < 5; ++comp) {
      float a = 0.f;
      #pragma unroll
      for (int g = 0; g < 16; ++g) a += lred[tid][g][comp];
      partial_s[((size_t)b*80 + tid*5 + comp)*256 + ch] = a;
    }
  }
  if (tid == 64) partial_b[bid] = lbg[0] + lbg[1] + lbg[2] + lbg[3];
}

// ---------------- kernel 2: reduce partials -> der, seedbg ----------------
// grid 8 x 256. der[seg][8] = {cx, cy, sexp, act, sbar, cnt, var, pad}
__global__ void __launch_bounds__(256) k_reduce(
    const float* __restrict__ partial_s, const float* __restrict__ partial_b,
    float* __restrict__ seedbg, float* __restrict__ der) {
  const int b = blockIdx.x;
  const int tid = threadIdx.x;
  const int w = tid >> 6, l = tid & 63;
  __shared__ float lsum[80];
  __shared__ float lsb[4];
  #pragma unroll
  for (int i = 0; i < 20; ++i) {
    int s = w + 4*i;
    const float* row = partial_s + ((size_t)b*80 + s)*256;
    float a = row[l] + row[l+64] + row[l+128] + row[l+192];
    #pragma unroll
    for (int off = 32; off; off >>= 1) a += __shfl_down(a, off);
    if (l == 0) lsum[s] = a;
  }
  {
    float a = partial_b[(size_t)tid*8 + b];   // ch = tid in [0,256)
    #pragma unroll
    for (int off = 32; off; off >>= 1) a += __shfl_down(a, off);
    if (l == 0) lsb[w] = a;
  }
  __syncthreads();
  if (tid == 64) seedbg[b] = lsb[0] + lsb[1] + lsb[2] + lsb[3];
  if (tid < KK) {
    float cnt  = lsum[tid*5+0];
    float safe = fmaxf(cnt, 1.f);
    float rs   = fast_rcp(safe);
    float cx = lsum[tid*5+1]*rs;
    float cy = lsum[tid*5+2]*rs;
    float sb = lsum[tid*5+3]*rs;
    float sq = lsum[tid*5+4];
    float* dd = der + (b*KK + tid)*8;
    dd[0] = cx; dd[1] = cy;
    dd[2] = __expf(10.f*sb);
    dd[3] = (cnt > 0.f) ? 1.f : 0.f;
    dd[4] = sb;
    dd[5] = cnt;
    dd[6] = sq - cnt*sb*sb;      // = Σ(σ−s̄)² over mask
  }
}

// ---------------- kernel 3: unified 16-instance hist + fg seed loss -------
// grid 1024: b = bid&7, ch = bid>>3 in [0,128); 2048 px/block.
// DECORRELATED pixel map: 16-lane group g handles its own 128-px chunk
// (different rows/positions), so within a wave the 4 groups produce
// uncorrelated buckets -> same-address LDS-atomic multiplicity drops from
// ~64-lane correlated to ~2-3 within each group. Hist rows padded to 200
// words (200%32=8) to stagger banks across k.
__global__ void __launch_bounds__(256, 4) k_hist(
    const float* __restrict__ pred, const int* __restrict__ inst,
    const float* __restrict__ der, unsigned int* __restrict__ hist,
    float* __restrict__ partial_v /*[1024]*/) {
  const int bid = blockIdx.x;
  const int b  = bid & 7;
  const int ch = bid >> 3;
  const int tid = threadIdx.x;
  const int g = tid >> 4, l4 = tid & 15;   // 16 groups x 16 lanes
  __shared__ unsigned int lh[KK][NBP];
  __shared__ float sder[KK][4];   // cx, cy, sexp, act
  __shared__ float lsl[4];
  if (tid < KK) {
    const float* dd = der + (b*KK + tid)*8;
    sder[tid][0] = dd[0]; sder[tid][1] = dd[1];
    sder[tid][2] = dd[2]; sder[tid][3] = dd[3];
  }
  for (int i = tid; i < KK*NBP; i += 256) ((unsigned int*)lh)[i] = 0u;
  __syncthreads();
  float cxa[KK], cya[KK], sea[KK]; bool aca[KK];
  #pragma unroll
  for (int k = 0; k < KK; ++k) {
    cxa[k] = sder[k][0]; cya[k] = sder[k][1];
    sea[k] = sder[k][2]; aca[k] = sder[k][3] > 0.f;
  }
  const float inv = 1.f/511.f;
  const float* pbx = pred + (size_t)b*4*NPIX;
  const float* pby = pbx + NPIX;
  const float* pbd = pbx + 3*NPIX;   // seed channel
  const int*   ib  = inst + (size_t)b*NPIX;
  const int base = ch*2048 + g*128;  // group-private 128-px chunk
  float sloss = 0.f;
  #pragma unroll
  for (int it = 0; it < 2; ++it) {
    const int p = base + it*64 + l4*4;
    float4 px = *(const float4*)(pbx + p);
    float4 py = *(const float4*)(pby + p);
    int4   iv = *(const int4*)(ib + p);
    float4 dv = *(const float4*)(pbd + p);
    const float ym  = (float)(p >> 9) * inv;
    const float xm0 = (float)(p & (WW-1)) * inv;
    float pxa[4] = {px.x, px.y, px.z, px.w};
    float pya[4] = {py.x, py.y, py.z, py.w};
    int   ida[4] = {iv.x, iv.y, iv.z, iv.w};
    float sda[4] = {dv.x, dv.y, dv.z, dv.w};
    #pragma unroll
    for (int j = 0; j < 4; ++j) {
      float sex = fast_tanh(pxa[j]) + xm0 + (float)j*inv;
      float sey = fast_tanh(pya[j]) + ym;
      int id = ida[j];
      float down = 0.f;
      #pragma unroll
      for (int k = 0; k < KK; ++k) {
        if (aca[k]) {
          float dx = sex - cxa[k], dy = sey - cya[k];
          float d = __expf(-sea[k]*(dx*dx + dy*dy));
          bool fg = (id == k+1);
          float u  = fg ? (1.f - d) : d;
          int bkt = (int)(u * (float)NB);
          bkt = bkt < (NB-1) ? bkt : (NB-1);
          atomicAdd(&lh[k][bkt], fg ? 0x10001u : 1u);
          down = fg ? d : down;
        }
      }
      if (id >= 1) {
        float dsee = fast_sigmoid(sda[j]) - down;
        sloss = fmaf(dsee, dsee, sloss);
      }
    }
  }
  __syncthreads();
  // flush 16 hists (first NB words of each padded row) -> disjoint regions
  #pragma unroll
  for (int k = 0; k < KK; ++k) {
    unsigned int* gh = hist + ((size_t)(b*KK + k)*CHV + ch)*NB;
    if (tid < NB) gh[tid] = lh[k][tid];
  }
  // block-reduce seed loss -> 1 float per block
  #pragma unroll
  for (int off = 32; off; off >>= 1) sloss += __shfl_down(sloss, off);
  if ((tid & 63) == 0) lsl[tid >> 6] = sloss;
  __syncthreads();
  if (tid == 0) partial_v[bid] = lsl[0] + lsl[1] + lsl[2] + lsl[3];
}

// ---------------- kernel 4: lovasz, 2-phase (collapse + scan) -------------
__global__ void __launch_bounds__(256) k_lovasz(
    const unsigned int* __restrict__ hist,
    const float* __restrict__ der, float* __restrict__ instl) {
  const int seg = blockIdx.x;           // b*K + k
  const int tid = threadIdx.x;
  __shared__ float nbL[NB], fbL[NB];
  const float gts = der[seg*8 + 5];
  const unsigned int* h = hist + (size_t)seg*CHV*NB;
  if (tid < NB) {
    unsigned int nlo = 0, nhi = 0;
    #pragma unroll 8
    for (int c = 0; c < CHV; ++c) {
      unsigned int v = h[(size_t)c*NB + tid];
      nlo += v & 0xffffu; nhi += v >> 16;
    }
    nbL[tid] = (float)nlo; fbL[tid] = (float)nhi;
  }
  __syncthreads();
  if (tid >= 64) return;
  const int lane = tid;
  if (gts <= 0.f) { if (lane == 0) instl[seg] = 0.f; return; }
  float carryN = 0.f, carryF = 0.f, lsum = 0.f;
  #pragma unroll
  for (int it = 0; it < NB/64; ++it) {
    int bkt = NB - 1 - (it*64 + lane);   // descending error order
    float nb = nbL[bkt], fb = fbL[bkt];
    float sn = nb, sf = fb;
    #pragma unroll
    for (int off = 1; off < 64; off <<= 1) {
      float tn = __shfl_up(sn, off);
      float tf = __shfl_up(sf, off);
      if (lane >= off) { sn += tn; sf += tf; }
    }
    float Nb = carryN + sn - nb;        // exclusive prefix
    float Fb = carryF + sf - fb;
    if (nb > 0.f) {
      float e  = ((float)bkt + 0.5f) * (2.0f/(float)NB);
      float j0 = 1.f - (gts - Fb) / (gts + Nb - Fb);
      float N1 = Nb + nb, F1 = Fb + fb;
      float j1 = 1.f - (gts - F1) / (gts + N1 - F1);
      lsum += e * (j1 - j0);
    }
    carryN += __shfl(sn, 63);
    carryF += __shfl(sf, 63);
  }
  #pragma unroll
  for (int off = 32; off; off >>= 1) lsum += __shfl_down(lsum, off);
  if (lane == 0) instl[seg] = lsum;
}

// ---------------- kernel 5: combine ---------------------------------------
__global__ void __launch_bounds__(256) k_final(
    const float* __restrict__ partial_v, const float* __restrict__ der,
    const float* __restrict__ instl, const float* __restrict__ seedbg,
    float* __restrict__ out) {
  __shared__ float vtmp[256];
  const int tid = threadIdx.x;
  {
    const int b8 = tid >> 5, j = tid & 31;
    float a = 0.f;
    #pragma unroll
    for (int i = 0; i < 4; ++i) a += partial_v[(size_t)(j + 32*i)*8 + b8];
    vtmp[tid] = a;
  }
  __syncthreads();
  float myv = 0.f;
  if (tid < BB) {
    int b = tid;
    float svl = 0.f;
    #pragma unroll
    for (int j = 0; j < 32; ++j) svl += vtmp[b*32 + j];
    float obj = 0.f, il = 0.f, vr = 0.f;
    for (int k = 0; k < KK; ++k) {
      int seg = b*KK + k;
      float cnt = der[seg*8 + 5];
      if (cnt > 0.f) {
        obj += 1.f;
        il  += instl[seg];
        vr  += der[seg*8 + 6] / cnt;   // var/(N_SIGMA*safe), safe==cnt
      }
    }
    float so = fmaxf(obj, 1.f);
    myv = il/so + 10.f*vr/so + (seedbg[b] + svl)/(float)NPIX;
  }
  #pragma unroll
  for (int off = 4; off; off >>= 1) myv += __shfl_down(myv, off);
  if (tid == 0) out[0] = myv * (1.f/(float)BB);
}

extern "C" void kernel_launch(void* const* d_in, const int* in_sizes, int n_in,
                              void* d_out, int out_size, void* d_ws, size_t ws_size,
                              hipStream_t stream) {
  const float* pred = (const float*)d_in[0];
  const int*   inst = (const int*)d_in[1];
  const int*   lab  = (const int*)d_in[2];
  float* out = (float*)d_out;

  // ws layout (~13.3 MB used of 256 MiB); all fully overwritten every call.
  float* der       = (float*)d_ws;                         // 128*8 f32 @ 0
  float* seedbg    = (float*)((char*)d_ws + 4096);         // 8 f32
  float* instl     = (float*)((char*)d_ws + 4160);         // 128 f32
  float* partial_b = (float*)((char*)d_ws + 8192);         // 2048 f32
  float* partial_v = (float*)((char*)d_ws + 16384);        // 1024 f32
  float* partial_s = (float*)((char*)d_ws + 24576);        // 8*80*256 f32 (640KB)
  unsigned int* hist = (unsigned int*)((char*)d_ws + 679936); // 128*128*192*4 = 12.6MB

  k_sums  <<<BB*256, 256, 0, stream>>>(pred, inst, lab, partial_s, partial_b);
  k_reduce<<<BB, 256, 0, stream>>>(partial_s, partial_b, seedbg, der);
  k_hist  <<<BB*CHV, 256, 0, stream>>>(pred, inst, der, hist, partial_v);
  k_lovasz<<<BB*KK, 256, 0, stream>>>(hist, der, instl);
  k_final <<<1, 256, 0, stream>>>(partial_v, der, instl, seedbg, out);
}